// Round 11
// baseline (777.296 us; speedup 1.0000x reference)
//
#include <hip/hip_runtime.h>

// ---------------------------------------------------------------------------
// Conformer encoder, MI355X bf16-MFMA implementation.
// Round 10: TRUE counted-vmcnt pipelines. __syncthreads() re-drains vmcnt to 0
// (compiler semantics), so round-9's counted wait never took effect. Both
// GEMMs now use raw __builtin_amdgcn_s_barrier() with asm "vmcnt(N) lgkmcnt(0)"
// (8-phase-template pattern): gemm2 = 3-buf BK=64; gemmB = 3-buf BK=32 with
// superrow XOR swizzle (2-way bank aliasing = free), 3 blocks/CU.
// ---------------------------------------------------------------------------

typedef unsigned short u16;
typedef unsigned int u32;
typedef __attribute__((ext_vector_type(8))) short bf16x8;
typedef __attribute__((ext_vector_type(4))) float f32x4;

#define DI __device__ __forceinline__

constexpr int CT = 512;     // sequence length T
constexpr int CD = 512;     // model dim D
constexpr int CH = 8;       // heads
constexpr int CDK = 64;     // head dim
constexpr int CDFF = 2048;  // ffn dim
constexpr int CNBT = 4096;  // B*T
constexpr int CL = 4;       // layers

DI u16 f2bf(float f) {
  u32 u = __builtin_bit_cast(u32, f);
  u = u + 0x7fffu + ((u >> 16) & 1u);
  return (u16)(u >> 16);
}
DI float bf2f(u16 h) { u32 u = ((u32)h) << 16; return __builtin_bit_cast(float, u); }
DI u32 pack2(float a, float b) { return (u32)f2bf(a) | ((u32)f2bf(b) << 16); }
DI float sigm(float x) { return 1.0f / (1.0f + __expf(-x)); }

DI f32x4 MFMA(bf16x8 a, bf16x8 b, f32x4 c) {
  return __builtin_amdgcn_mfma_f32_16x16x32_bf16(a, b, c, 0, 0, 0);
}

DI void gload16(const void* g, void* l) {
  __builtin_amdgcn_global_load_lds((const __attribute__((address_space(1))) void*)g,
                                   (__attribute__((address_space(3))) void*)l, 16, 0, 0);
}

DI float wsum(float v) {
#pragma unroll
  for (int o = 32; o > 0; o >>= 1) v += __shfl_xor(v, o, 64);
  return v;
}

// ------------------------- weight conversion -------------------------------
// 32x32 transpose tile helper body: in [R,C] f32 -> out [C,R] bf16
DI void tbody(const float* ip, u16* op, int R, int C, int c0, int r0,
              int tx, int ty) {
  __shared__ float t[32][33];
#pragma unroll
  for (int i = ty; i < 32; i += 8)
    t[i][tx] = ip[(long)(r0 + i) * C + c0 + tx];
  __syncthreads();
#pragma unroll
  for (int i = ty; i < 32; i += 8)
    op[(long)(c0 + i) * R + r0 + tx] = f2bf(t[tx][i]);
}

// pair transposer: z<4 -> (in0,out0,layer z), else (in1,out1,layer z-4)
__global__ __launch_bounds__(256) void tconv2x_k(const float* __restrict__ in0,
                                                 const float* __restrict__ in1,
                                                 u16* __restrict__ out0,
                                                 u16* __restrict__ out1,
                                                 int R, int C) {
  int z = blockIdx.z;
  int l = z & 3;
  const float* ip = (z < 4 ? in0 : in1) + (long)l * R * C;
  u16* op = (z < 4 ? out0 : out1) + (long)l * R * C;
  tbody(ip, op, R, C, blockIdx.x * 32, blockIdx.y * 32, threadIdx.x, threadIdx.y);
}

// 5-way 512x512 transposer: Wq/Wk/Wv -> wt_qkv rows {0,512,1024}, Wo, Wpos
__global__ __launch_bounds__(256) void tconvQ_k(
    const float* __restrict__ Wq, const float* __restrict__ Wk,
    const float* __restrict__ Wv, const float* __restrict__ Wo,
    const float* __restrict__ Wpos, u16* __restrict__ wt_qkv,
    u16* __restrict__ wt_o, u16* __restrict__ wt_pos) {
  int z = blockIdx.z;
  int sel = z >> 2, l = z & 3;
  const float* ip;
  u16* op;
  const long S = 512L * 512;
  switch (sel) {
    case 0: ip = Wq + l * S; op = wt_qkv + (long)l * 1536 * 512; break;
    case 1: ip = Wk + l * S; op = wt_qkv + (long)l * 1536 * 512 + S; break;
    case 2: ip = Wv + l * S; op = wt_qkv + (long)l * 1536 * 512 + 2 * S; break;
    case 3: ip = Wo + l * S; op = wt_o + l * S; break;
    default: ip = Wpos + l * S; op = wt_pos + l * S; break;
  }
  tbody(ip, op, 512, 512, blockIdx.x * 32, blockIdx.y * 32, threadIdx.x, threadIdx.y);
}

// fp32 -> bf16 flat (pw2)
__global__ __launch_bounds__(256) void cvt_k(const float* __restrict__ in,
                                             u16* __restrict__ out, long nIn, long nOut,
                                             long inZ, long outZ) {
  long i = ((long)blockIdx.x * 256 + threadIdx.x) * 4;
  if (i >= nOut) return;
  const float* ip = in + (long)blockIdx.y * inZ;
  u16* op = out + (long)blockIdx.y * outZ;
  u16 o[4];
#pragma unroll
  for (int j = 0; j < 4; ++j) {
    long idx = i + j;
    o[j] = (idx < nIn) ? f2bf(ip[idx]) : (u16)0;
  }
  uint2 st;
  st.x = (u32)o[0] | ((u32)o[1] << 16);
  st.y = (u32)o[2] | ((u32)o[3] << 16);
  *(uint2*)&op[i] = st;
}

// pw1_w [L][1024][512] f32 -> bf16 with 16-row a/g interleave
__global__ __launch_bounds__(256) void pwperm_k(const float* __restrict__ in,
                                                u16* __restrict__ out) {
  int l = blockIdx.y;
  long i = (long)blockIdx.x * 256 + threadIdx.x;  // quads
  long n = i >> 7;
  int c = (int)(i & 127) * 4;
  int q = (int)(n >> 4) & 1;
  long r = (q ? 512 : 0) + ((n >> 5) << 4) + (n & 15);
  const float* ip = in + ((long)l * 1024 + r) * 512 + c;
  float4 v = *(const float4*)ip;
  u16* op = out + ((long)l * 1024 + n) * 512 + c;
  uint2 st;
  st.x = pack2(v.x, v.y);
  st.y = pack2(v.z, v.w);
  *(uint2*)op = st;
}

// merged small setup: y=0 pos cvt (pad to 1024 rows); y=1 dw transpose;
// y=2 qkv bias pack
__global__ __launch_bounds__(256) void setup3_k(
    const float* __restrict__ in_pos, u16* __restrict__ posbf,
    const float* __restrict__ dw_w, float* __restrict__ dwT,
    const float* __restrict__ bq, const float* __restrict__ bk,
    const float* __restrict__ bv, float* __restrict__ qkvb) {
  int y = blockIdx.y;
  long x = blockIdx.x;
  int tid = threadIdx.x;
  if (y == 0) {
    long i = (x * 256 + tid) * 4;
    const long nIn = 1023L * 512, nOut = 1024L * 512;
    if (i >= nOut) return;
    u16 o[4];
#pragma unroll
    for (int j = 0; j < 4; ++j) {
      long idx = i + j;
      o[j] = (idx < nIn) ? f2bf(in_pos[idx]) : (u16)0;
    }
    uint2 st;
    st.x = (u32)o[0] | ((u32)o[1] << 16);
    st.y = (u32)o[2] | ((u32)o[3] << 16);
    *(uint2*)&posbf[i] = st;
  } else if (y == 1) {
    long idx = x * 256 + tid;
    if (idx >= 4L * 31 * 512) return;
    long l = idx / (31 * 512);
    int rem = (int)(idx % (31 * 512));
    int k = rem >> 9, d = rem & 511;
    dwT[idx] = dw_w[l * 512 * 31 + d * 31 + k];
  } else {
    long idx = x * 256 + tid;
    if (idx >= 4L * 1536) return;
    int z = (int)(idx / 1536), j = (int)(idx % 1536);
    float v;
    if (j < 512) v = bq[z * 512 + j];
    else if (j < 1024) v = bk[z * 512 + j - 512];
    else v = bv[z * 512 + j - 1024];
    qkvb[idx] = v;
  }
}

// ------------------------------- LayerNorm ---------------------------------
template <int F32OUT>
__global__ __launch_bounds__(256) void ln_k(const float* in, void* out,
                                            const float* gw, const float* bw) {
  int tid = threadIdx.x, wid = tid >> 6, lane = tid & 63;
  long row = (long)blockIdx.x * 4 + wid;
  const float* x = in + row * CD + lane * 8;
  float4 v0 = *(const float4*)x;
  float4 v1 = *(const float4*)(x + 4);
  float s = v0.x + v0.y + v0.z + v0.w + v1.x + v1.y + v1.z + v1.w;
  float q = v0.x * v0.x + v0.y * v0.y + v0.z * v0.z + v0.w * v0.w +
            v1.x * v1.x + v1.y * v1.y + v1.z * v1.z + v1.w * v1.w;
  s = wsum(s);
  q = wsum(q);
  float mean = s * (1.0f / CD);
  float var = q * (1.0f / CD) - mean * mean;
  float rs = rsqrtf(var + 1e-5f);
  int c = lane * 8;
  float4 g0 = *(const float4*)(gw + c), g1 = *(const float4*)(gw + c + 4);
  float4 b0 = *(const float4*)(bw + c), b1 = *(const float4*)(bw + c + 4);
  float y0 = (v0.x - mean) * rs * g0.x + b0.x;
  float y1 = (v0.y - mean) * rs * g0.y + b0.y;
  float y2 = (v0.z - mean) * rs * g0.z + b0.z;
  float y3 = (v0.w - mean) * rs * g0.w + b0.w;
  float y4 = (v1.x - mean) * rs * g1.x + b1.x;
  float y5 = (v1.y - mean) * rs * g1.y + b1.y;
  float y6 = (v1.z - mean) * rs * g1.z + b1.z;
  float y7 = (v1.w - mean) * rs * g1.w + b1.w;
  if (F32OUT) {
    float* o = (float*)out + row * CD + c;
    *(float4*)o = make_float4(y0, y1, y2, y3);
    *(float4*)(o + 4) = make_float4(y4, y5, y6, y7);
  } else {
    u16* o = (u16*)out + row * CD + c;
    uint4 pk;
    pk.x = pack2(y0, y1);
    pk.y = pack2(y2, y3);
    pk.z = pack2(y4, y5);
    pk.w = pack2(y6, y7);
    *(uint4*)o = pk;
  }
}

// layer-0: cur = in_x (copy) and ybf = LN(in_x; ln1), one read pass
__global__ __launch_bounds__(256) void ln_cp_k(const float* __restrict__ in,
                                               float* __restrict__ cur,
                                               u16* __restrict__ ybf,
                                               const float* gw, const float* bw) {
  int tid = threadIdx.x, wid = tid >> 6, lane = tid & 63;
  long row = (long)blockIdx.x * 4 + wid;
  const float* x = in + row * CD + lane * 8;
  float v[8];
  *(float4*)&v[0] = *(const float4*)x;
  *(float4*)&v[4] = *(const float4*)(x + 4);
  float* cx = cur + row * CD + lane * 8;
  *(float4*)cx = *(float4*)&v[0];
  *(float4*)(cx + 4) = *(float4*)&v[4];
  float s = 0.f, q = 0.f;
#pragma unroll
  for (int j = 0; j < 8; ++j) { s += v[j]; q += v[j] * v[j]; }
  s = wsum(s);
  q = wsum(q);
  float mean = s * (1.0f / CD);
  float var = q * (1.0f / CD) - mean * mean;
  float rs = rsqrtf(var + 1e-5f);
  int c = lane * 8;
  float y[8];
#pragma unroll
  for (int j = 0; j < 8; ++j) y[j] = (v[j] - mean) * rs * gw[c + j] + bw[c + j];
  u16* o = ybf + row * CD + c;
  uint4 pk;
  pk.x = pack2(y[0], y[1]);
  pk.y = pack2(y[2], y[3]);
  pk.z = pack2(y[4], y[5]);
  pk.w = pack2(y[6], y[7]);
  *(uint4*)o = pk;
}

// fused lnO (fp32 -> cur) + ln1-of-next-layer (bf16 -> ybf), one read pass
__global__ __launch_bounds__(256) void lnln_k(float* cur, u16* ybf,
                                              const float* gO, const float* bO,
                                              const float* g1, const float* b1) {
  int tid = threadIdx.x, wid = tid >> 6, lane = tid & 63;
  long row = (long)blockIdx.x * 4 + wid;
  float* x = cur + row * CD + lane * 8;
  float v[8];
  *(float4*)&v[0] = *(const float4*)x;
  *(float4*)&v[4] = *(const float4*)(x + 4);
  float s = 0.f, q = 0.f;
#pragma unroll
  for (int j = 0; j < 8; ++j) { s += v[j]; q += v[j] * v[j]; }
  s = wsum(s);
  q = wsum(q);
  float mean = s * (1.0f / CD);
  float var = q * (1.0f / CD) - mean * mean;
  float rs = rsqrtf(var + 1e-5f);
  int c = lane * 8;
  float y[8];
#pragma unroll
  for (int j = 0; j < 8; ++j) y[j] = (v[j] - mean) * rs * gO[c + j] + bO[c + j];
  *(float4*)x = *(float4*)&y[0];
  *(float4*)(x + 4) = *(float4*)&y[4];
  float s2 = 0.f, q2 = 0.f;
#pragma unroll
  for (int j = 0; j < 8; ++j) { s2 += y[j]; q2 += y[j] * y[j]; }
  s2 = wsum(s2);
  q2 = wsum(q2);
  float mean2 = s2 * (1.0f / CD);
  float var2 = q2 * (1.0f / CD) - mean2 * mean2;
  float rs2 = rsqrtf(var2 + 1e-5f);
  float z[8];
#pragma unroll
  for (int j = 0; j < 8; ++j) z[j] = (y[j] - mean2) * rs2 * g1[c + j] + b1[c + j];
  u16* o = ybf + row * CD + c;
  uint4 pk;
  pk.x = pack2(z[0], z[1]);
  pk.y = pack2(z[2], z[3]);
  pk.z = pack2(z[4], z[5]);
  pk.w = pack2(z[6], z[7]);
  *(uint4*)o = pk;
}

// --------------------------------- GEMM v2 (64x64) -------------------------
// 3-buffer counted-vmcnt pipeline with RAW barriers (no hidden vmcnt(0)
// drain): per K-tile {vmcnt(4)+lgkmcnt(0); s_barrier; stage kt+2; compute}.
// EPI: 0 store bf16 | 3 res += alpha*(v+bias)
template <int EPI, int SPLITK>
__global__ __launch_bounds__(256, 3) void gemm2_k(
    const u16* __restrict__ A, const u16* __restrict__ B, void* C,
    const float* __restrict__ bias, float alpha, int lda, int ldb, int ldc, int Kd) {
  __shared__ u16 lds[3][2][64 * 64];  // [buf][A/B][row*64]
  const int tid = threadIdx.x, wid = tid >> 6, lane = tid & 63;
  const int m0 = blockIdx.x * 64, n0 = blockIdx.y * 64;
  const int wm = wid >> 1, wn = wid & 1;
  const int fr = lane & 15, fq = lane >> 4;
  const f32x4 vz = {0.f, 0.f, 0.f, 0.f};
  f32x4 acc[2][2] = {{vz, vz}, {vz, vz}};

  const int Kc = Kd / SPLITK;
  const int kb0 = (SPLITK > 1) ? blockIdx.z * Kc : 0;
  const int nK = Kc / 64;

  auto stage = [&](int buf, int kt) {
    const int k0 = kb0 + kt * 64;
#pragma unroll
    for (int r = 0; r < 2; ++r) {
      int bi = r * 4096 + tid * 16;
      int row = bi >> 7;
      int ch = ((bi >> 4) & 7) ^ (row & 7);  // inverse swizzle on source
      gload16(A + (long)(m0 + row) * lda + k0 + ch * 8,
              (char*)&lds[buf][0][0] + r * 4096 + wid * 1024);
      gload16(B + (long)(n0 + row) * ldb + k0 + ch * 8,
              (char*)&lds[buf][1][0] + r * 4096 + wid * 1024);
    }
  };

  stage(0, 0);
  if (nK > 1) stage(1, 1);
  for (int kt = 0; kt < nK; ++kt) {
    const int buf = kt % 3;
    if (kt + 1 < nK)
      asm volatile("s_waitcnt vmcnt(4) lgkmcnt(0)" ::: "memory");
    else
      asm volatile("s_waitcnt vmcnt(0) lgkmcnt(0)" ::: "memory");
    __builtin_amdgcn_s_barrier();   // raw: prefetch loads stay in flight
    if (kt + 2 < nK) stage((kt + 2) % 3, kt + 2);
    bf16x8 af[2][2], bfv[2][2];
#pragma unroll
    for (int ks = 0; ks < 2; ++ks) {
      int ch = ks * 4 + fq;
#pragma unroll
      for (int i = 0; i < 2; ++i) {
        int arow = wm * 32 + i * 16 + fr;
        af[ks][i] = *(const bf16x8*)((const char*)&lds[buf][0][0] + arow * 128 +
                                     ((ch ^ (arow & 7)) << 4));
        int brow = wn * 32 + i * 16 + fr;
        bfv[ks][i] = *(const bf16x8*)((const char*)&lds[buf][1][0] + brow * 128 +
                                      ((ch ^ (brow & 7)) << 4));
      }
    }
#pragma unroll
    for (int ks = 0; ks < 2; ++ks)
#pragma unroll
      for (int mi = 0; mi < 2; ++mi)
#pragma unroll
        for (int ni = 0; ni < 2; ++ni)
          acc[mi][ni] = MFMA(af[ks][mi], bfv[ks][ni], acc[mi][ni]);
  }

#pragma unroll
  for (int mi = 0; mi < 2; ++mi) {
    const int gmB = m0 + wm * 32 + mi * 16 + fq * 4;
#pragma unroll
    for (int ni = 0; ni < 2; ++ni) {
      const int gn = n0 + wn * 32 + ni * 16 + fr;
      float bv_ = 0.f;
      if constexpr (EPI == 3) bv_ = bias[gn];
#pragma unroll
      for (int r = 0; r < 4; ++r) {
        const int gm = gmB + r;
        float v = acc[mi][ni][r];
        long idx = (long)gm * ldc + gn;
        if constexpr (EPI == 0) ((u16*)C)[idx] = f2bf(v);
        else if constexpr (EPI == 3) {
          float* R = (float*)C;
          if constexpr (SPLITK > 1) {
            float add = alpha * (v + (blockIdx.z == 0 ? bv_ : 0.f));
            atomicAdd(&R[idx], add);
          } else {
            R[idx] += alpha * (v + bv_);
          }
        }
      }
    }
  }
}

// --------------------------------- GEMM vB (128x128, BK=32, 3-buf) ---------
// 3-buffer counted-vmcnt pipeline (4 loads/stage), raw barriers, 3 blocks/CU.
// Superrow swizzle: LDS [64 superrows][8 x 16B chunks]; slot c' at superrow sr
// holds (row = 2*sr + (cc>>2), kchunk = cc&3) with cc = c' ^ (sr&7).
// Reader (arow, fq): sr=arow>>1, cc=((arow&1)<<2)|fq -> 2-way bank alias (free).
// XCD-bijective tile swizzle (T1; grid %8==0).
// EPI: 2 +bias swish | 7 GLU-packed | 8 qkv (+v-transpose to Caux)
template <int EPI>
__global__ __launch_bounds__(256, 3) void gemmB_k(
    const u16* __restrict__ A, const u16* __restrict__ B, void* C,
    u16* __restrict__ Caux, const float* __restrict__ bias,
    int lda, int ldb, int ldc, int Kd) {
  __shared__ u16 ldsA[3][128 * 32];
  __shared__ u16 ldsB[3][128 * 32];
  const int tid = threadIdx.x, wid = tid >> 6, lane = tid & 63;
  // T1 XCD swizzle: consecutive tiles (same B-panel) -> same XCD L2
  const int nwg = gridDim.x * gridDim.y;
  int lin = blockIdx.y * gridDim.x + blockIdx.x;
  lin = (lin & 7) * (nwg >> 3) + (lin >> 3);
  const int m0 = (lin % gridDim.x) * 128, n0 = (lin / gridDim.x) * 128;
  const int wm = wid >> 1, wn = wid & 1;
  const int fr = lane & 15, fq = lane >> 4;
  const f32x4 vz = {0.f, 0.f, 0.f, 0.f};
  f32x4 acc[4][4];
#pragma unroll
  for (int mi = 0; mi < 4; ++mi)
#pragma unroll
    for (int ni = 0; ni < 4; ++ni) acc[mi][ni] = vz;
  const int nK = Kd / 32;

  auto stage = [&](int buf, int kt) {
    const int k0 = kt * 32;
#pragma unroll
    for (int r = 0; r < 2; ++r) {
      int bi = r * 4096 + tid * 16;      // byte offset within 8KB tile
      int sr = bi >> 7;                   // superrow (2 rows / 128B)
      int cc = ((bi >> 4) & 7) ^ (sr & 7);
      int row = 2 * sr + (cc >> 2);
      int kc = cc & 3;
      gload16(A + (long)(m0 + row) * lda + k0 + kc * 8,
              (char*)&ldsA[buf][0] + r * 4096 + wid * 1024);
      gload16(B + (long)(n0 + row) * ldb + k0 + kc * 8,
              (char*)&ldsB[buf][0] + r * 4096 + wid * 1024);
    }
  };

  stage(0, 0);
  if (nK > 1) stage(1, 1);
  for (int kt = 0; kt < nK; ++kt) {
    const int buf = kt % 3;
    if (kt + 1 < nK)
      asm volatile("s_waitcnt vmcnt(4) lgkmcnt(0)" ::: "memory");
    else
      asm volatile("s_waitcnt vmcnt(0) lgkmcnt(0)" ::: "memory");
    __builtin_amdgcn_s_barrier();   // raw: prefetch loads stay in flight
    if (kt + 2 < nK) stage((kt + 2) % 3, kt + 2);
    bf16x8 af[4], bfv[4];
#pragma unroll
    for (int i = 0; i < 4; ++i) {
      int arow = wm * 64 + i * 16 + fr;
      int srA = arow >> 1;
      int ccA = ((arow & 1) << 2) | fq;
      af[i] = *(const bf16x8*)((const char*)&ldsA[buf][0] + srA * 128 +
                               ((ccA ^ (srA & 7)) << 4));
      int brow = wn * 64 + i * 16 + fr;
      int srB = brow >> 1;
      int ccB = ((brow & 1) << 2) | fq;
      bfv[i] = *(const bf16x8*)((const char*)&ldsB[buf][0] + srB * 128 +
                                ((ccB ^ (srB & 7)) << 4));
    }
#pragma unroll
    for (int mi = 0; mi < 4; ++mi)
#pragma unroll
      for (int ni = 0; ni < 4; ++ni)
        acc[mi][ni] = MFMA(af[mi], bfv[ni], acc[mi][ni]);
  }

  if constexpr (EPI == 2) {
#pragma unroll
    for (int mi = 0; mi < 4; ++mi) {
      const int gmB = m0 + wm * 64 + mi * 16 + fq * 4;
#pragma unroll
      for (int ni = 0; ni < 4; ++ni) {
        const int gn = n0 + wn * 64 + ni * 16 + fr;
        float bv_ = bias[gn];
#pragma unroll
        for (int r = 0; r < 4; ++r) {
          float x = acc[mi][ni][r] + bv_;
          ((u16*)C)[(long)(gmB + r) * ldc + gn] = f2bf(x * sigm(x));
        }
      }
    }
  } else if constexpr (EPI == 7) {
#pragma unroll
    for (int mi = 0; mi < 4; ++mi) {
      const int gmB = m0 + wm * 64 + mi * 16 + fq * 4;
#pragma unroll
      for (int p = 0; p < 2; ++p) {
        const int ucol = (n0 >> 1) + wn * 32 + p * 16 + fr;
        float ba = bias[ucol], bg = bias[512 + ucol];
#pragma unroll
        for (int r = 0; r < 4; ++r) {
          float va = acc[mi][2 * p][r] + ba;
          float vg = acc[mi][2 * p + 1][r] + bg;
          ((u16*)C)[(long)(gmB + r) * 512 + ucol] = f2bf(va * sigm(vg));
        }
      }
    }
  } else if constexpr (EPI == 8) {
    if (n0 < 1024) {
#pragma unroll
      for (int mi = 0; mi < 4; ++mi) {
        const int gmB = m0 + wm * 64 + mi * 16 + fq * 4;
#pragma unroll
        for (int ni = 0; ni < 4; ++ni) {
          const int gn = n0 + wn * 64 + ni * 16 + fr;
          float bv_ = bias[gn];
#pragma unroll
          for (int r = 0; r < 4; ++r)
            ((u16*)C)[(long)(gmB + r) * ldc + gn] = f2bf(acc[mi][ni][r] + bv_);
        }
      }
    } else {
#pragma unroll
      for (int mi = 0; mi < 4; ++mi) {
        const int gmB = m0 + wm * 64 + mi * 16 + fq * 4;
        const int b = gmB >> 9, t = gmB & 511;
#pragma unroll
        for (int ni = 0; ni < 4; ++ni) {
          const int gn = n0 + wn * 64 + ni * 16 + fr;
          const int h = (gn - 1024) >> 6, d = (gn - 1024) & 63;
          float bv_ = bias[gn];
          uint2 pk;
          pk.x = pack2(acc[mi][ni][0] + bv_, acc[mi][ni][1] + bv_);
          pk.y = pack2(acc[mi][ni][2] + bv_, acc[mi][ni][3] + bv_);
          *(uint2*)&Caux[((long)(b * 8 + h) * 64 + d) * 512 + t] = pk;
        }
      }
    }
  }
}

// ---------------- fused rel-pos flash attention v2 -------------------------
__global__ __launch_bounds__(256, 2) void attn_k(
    const u16* __restrict__ qkvp, const u16* __restrict__ pball,
    const float* __restrict__ pbuL, const float* __restrict__ pbvL,
    const u16* __restrict__ vt, u16* __restrict__ out) {
  __shared__ u16 ldsK[2][64 * 64];    // [s][d] swizzled
  __shared__ u16 ldsP[2][128 * 64];   // [j][d] swizzled
  __shared__ u16 bd0s[4][16 * 80];    // per-wave bd band
  __shared__ u16 stile[4][16 * 64];   // per-wave P (swizzled rows)
  const int tid = threadIdx.x, wid = tid >> 6, lane = tid & 63;
  const int t0 = blockIdx.x * 64;
  const int bh = blockIdx.y, b = bh >> 3, h = bh & 7;
  const int fr = lane & 15, fq = lane >> 4;

  const u16* kbase = qkvp + (long)(b * CT) * 1536 + 512 + h * 64;
  const u16* pbase = pball + h * 64;
  const float* pu = pbuL + h * 64;
  const float* pv = pbvL + h * 64;

  const u16* qp = qkvp + (long)(b * CT + t0 + wid * 16 + fr) * 1536 + h * 64;
  bf16x8 qua[2], qva[2];
#pragma unroll
  for (int kk = 0; kk < 2; ++kk) {
    bf16x8 qw = *(const bf16x8*)(qp + kk * 32 + fq * 8);
    const float* bu = pu + kk * 32 + fq * 8;
    const float* bv = pv + kk * 32 + fq * 8;
#pragma unroll
    for (int j = 0; j < 8; ++j) {
      float qf = bf2f((u16)qw[j]);
      qua[kk][j] = (short)f2bf(qf + bu[j]);
      qva[kk][j] = (short)f2bf(qf + bv[j]);
    }
  }

  const f32x4 vz = {0.f, 0.f, 0.f, 0.f};
  f32x4 oacc[4] = {vz, vz, vz, vz};
  float m_run[4] = {-1e30f, -1e30f, -1e30f, -1e30f};
  float l_run[4] = {0.f, 0.f, 0.f, 0.f};
  const int jbw = (3 - wid) * 16;

  auto stage = [&](int buf, int st) {
    int s0 = st * 64, j0 = s0 - t0 + 448;
#pragma unroll
    for (int r = 0; r < 2; ++r) {
      int c = r * 256 + tid;
      int row = c >> 3, cs = (c & 7) ^ (row & 7);
      gload16(kbase + (long)(s0 + row) * 1536 + cs * 8,
              (char*)&ldsK[buf][0] + r * 4096 + wid * 1024);
    }
#pragma unroll
    for (int r = 0; r < 4; ++r) {
      int c = r * 256 + tid;
      int row = c >> 3, cs = (c & 7) ^ (row & 7);
      gload16(pbase + (long)(j0 + row) * 2048 + cs * 8,
              (char*)&ldsP[buf][0] + r * 4096 + wid * 1024);
    }
  };

  stage(0, 0);
  int cur = 0;
  for (int st = 0; st < 8; ++st) {
    const int s0 = st * 64;
    if (st + 1 < 8) {
      stage(cur ^ 1, st + 1);
      asm volatile("s_waitcnt vmcnt(6)" ::: "memory");
    } else {
      asm volatile("s_waitcnt vmcnt(0)" ::: "memory");
    }
    __syncthreads();

    bf16x8 vb[4][2];
#pragma unroll
    for (int ni = 0; ni < 4; ++ni)
#pragma unroll
      for (int kk = 0; kk < 2; ++kk)
        vb[ni][kk] = *(const bf16x8*)&vt[((long)bh * 64 + ni * 16 + fr) * 512 +
                                         s0 + kk * 32 + fq * 8];

    __builtin_amdgcn_s_setprio(1);
    f32x4 ac[4] = {vz, vz, vz, vz};
#pragma unroll
    for (int kk = 0; kk < 2; ++kk) {
#pragma unroll
      for (int ni = 0; ni < 4; ++ni) {
        int row = ni * 16 + fr;
        bf16x8 kb = *(const bf16x8*)((const char*)&ldsK[cur][0] +
                                     ((row * 128 + kk * 64 + fq * 16) ^ ((row & 7) << 4)));
        ac[ni] = MFMA(qua[kk], kb, ac[ni]);
      }
    }
    f32x4 bd[5] = {vz, vz, vz, vz, vz};
#pragma unroll
    for (int kk = 0; kk < 2; ++kk) {
#pragma unroll
      for (int nbi = 0; nbi < 5; ++nbi) {
        int row = jbw + nbi * 16 + fr;
        bf16x8 pb = *(const bf16x8*)((const char*)&ldsP[cur][0] +
                                     ((row * 128 + kk * 64 + fq * 16) ^ ((row & 7) << 4)));
        bd[nbi] = MFMA(qva[kk], pb, bd[nbi]);
      }
    }
    __builtin_amdgcn_s_setprio(0);
#pragma unroll
    for (int nbi = 0; nbi < 5; ++nbi)
#pragma unroll
      for (int r = 0; r < 4; ++r)
        bd0s[wid][(fq * 4 + r) * 80 + nbi * 16 + fr] = f2bf(bd[nbi][r]);

    float vals[4][4];
#pragma unroll
    for (int ni = 0; ni < 4; ++ni)
#pragma unroll
      for (int r = 0; r < 4; ++r) {
        int tlw = fq * 4 + r;
        int jcol = ni * 16 + fr + 15 - tlw;
        vals[ni][r] = (ac[ni][r] + bf2f(bd0s[wid][tlw * 80 + jcol])) * 0.125f;
      }
    float scf[4];
#pragma unroll
    for (int r = 0; r < 4; ++r) {
      float mx = fmaxf(fmaxf(vals[0][r], vals[1][r]), fmaxf(vals[2][r], vals[3][r]));
      mx = fmaxf(mx, __shfl_xor(mx, 1));
      mx = fmaxf(mx, __shfl_xor(mx, 2));
      mx = fmaxf(mx, __shfl_xor(mx, 4));
      mx = fmaxf(mx, __shfl_xor(mx, 8));
      float mnew = fmaxf(m_run[r], mx);
      scf[r] = __expf(m_run[r] - mnew);
      m_run[r] = mnew;
      float sum = 0.f;
#pragma unroll
      for (int ni = 0; ni < 4; ++ni) {
        float p = __expf(vals[ni][r] - mnew);
        vals[ni][r] = p;
        sum += p;
      }
      sum += __shfl_xor(sum, 1);
      sum += __shfl_xor(sum, 2);
      sum += __shfl_xor(sum, 4);
      sum += __shfl_xor(sum, 8);
      l_run[r] = l_run[r] * scf[r] + sum;
    }
#pragma unroll
    for (int ni = 0; ni < 4; ++ni)
#pragma unroll
      for (int r = 0; r < 4; ++r) {
        int tlw = fq * 4 + r;
        *(u16*)((char*)&stile[wid][0] +
                (((tlw * 128) + (ni * 16 + fr) * 2) ^ ((tlw & 7) << 4))) =
            f2bf(vals[ni][r]);
      }
#pragma unroll
    for (int ni = 0; ni < 4; ++ni)
#pragma unroll
      for (int r = 0; r < 4; ++r) oacc[ni][r] *= scf[r];
    __builtin_amdgcn_s_setprio(1);
#pragma unroll
    for (int kk = 0; kk < 2; ++kk) {
      bf16x8 pa = *(const bf16x8*)((const char*)&stile[wid][0] +
                                   ((fr * 128 + kk * 64 + fq * 16) ^ ((fr & 7) << 4)));
#pragma unroll
      for (int ni = 0; ni < 4; ++ni) oacc[ni] = MFMA(pa, vb[ni][kk], oacc[ni]);
    }
    __builtin_amdgcn_s_setprio(0);
    __syncthreads();
    cur ^= 1;
  }

  float inv[4];
#pragma unroll
  for (int r = 0; r < 4; ++r) inv[r] = 1.0f / l_run[r];
#pragma unroll
  for (int ni = 0; ni < 4; ++ni)
#pragma unroll
    for (int r = 0; r < 4; ++r) {
      long row = (long)(b * CT + t0 + wid * 16 + fq * 4 + r) * CD + h * CDK;
      out[row + ni * 16 + fr] = f2bf(oacc[ni][r] * inv[r]);
    }
}

// ------------------------------ conv module --------------------------------
// depthwise conv(K=31,pad 15) + dw_b + LN(cln) + swish.
__global__ __launch_bounds__(256) void conv2_k(const u16* __restrict__ u,
                                               const float* __restrict__ wT,
                                               const float* __restrict__ wb,
                                               const float* __restrict__ cg,
                                               const float* __restrict__ cb,
                                               u16* __restrict__ out) {
  constexpr int TT = 8;
  int tid = threadIdx.x, d0 = tid * 2;
  int b = blockIdx.y, t0 = blockIdx.x * TT;
  const u16* ub = u + ((long)b * CT) * CD + d0;

  u32 strip[TT + 30];
#pragma unroll
  for (int j = 0; j < TT + 30; ++j) {
    int tt = t0 + j - 15;
    strip[j] = ((unsigned)tt < (unsigned)CT) ? *(const u32*)(ub + (long)tt * CD) : 0u;
  }
  float2 bias = *(const float2*)(wb + d0);
  float a0[TT], a1[TT];
#pragma unroll
  for (int t = 0; t < TT; ++t) { a0[t] = bias.x; a1[t] = bias.y; }
#pragma unroll
  for (int k = 0; k < 31; ++k) {
    float2 wk = *(const float2*)(wT + k * CD + d0);
#pragma unroll
    for (int t = 0; t < TT; ++t) {
      u32 pr = strip[t + k];
      a0[t] += bf2f((u16)(pr & 0xffff)) * wk.x;
      a1[t] += bf2f((u16)(pr >> 16)) * wk.y;
    }
  }
  __shared__ float redS[4][TT], redQ[4][TT];
  int wid = tid >> 6, lane = tid & 63;
#pragma unroll
  for (int t = 0; t < TT; ++t) {
    float s = a0[t] + a1[t];
    float q = a0[t] * a0[t] + a1[t] * a1[t];
    s = wsum(s);
    q = wsum(q);
    if (lane == 0) { redS[wid][t] = s; redQ[wid][t] = q; }
  }
  __syncthreads();
  float2 g2 = *(const float2*)(cg + d0);
  float2 b2 = *(const float2*)(cb + d0);
#pragma unroll
  for (int t = 0; t < TT; ++t) {
    float s = redS[0][t] + redS[1][t] + redS[2][t] + redS[3][t];
    float q = redQ[0][t] + redQ[1][t] + redQ[2][t] + redQ[3][t];
    float mean = s * (1.f / 512), var = q * (1.f / 512) - mean * mean;
    float rs = rsqrtf(var + 1e-5f);
    float y0 = (a0[t] - mean) * rs * g2.x + b2.x;
    float y1 = (a1[t] - mean) * rs * g2.y + b2.y;
    y0 = y0 * sigm(y0);
    y1 = y1 * sigm(y1);
    *(u32*)(out + ((long)(b * CT + t0 + t)) * CD + d0) = pack2(y0, y1);
  }
}

// ---------------------------------------------------------------------------
extern "C" void kernel_launch(void* const* d_in, const int* in_sizes, int n_in,
                              void* d_out, int out_size, void* d_ws, size_t ws_size,
                              hipStream_t stream) {
  const float* in_x   = (const float*)d_in[0];
  const float* in_pos = (const float*)d_in[1];
  const float* ln1_g  = (const float*)d_in[2];
  const float* ln1_b  = (const float*)d_in[3];
  const float* ff1_w1 = (const float*)d_in[4];
  const float* ff1_b1 = (const float*)d_in[5];
  const float* ff1_w2 = (const float*)d_in[6];
  const float* ff1_b2 = (const float*)d_in[7];
  const float* lnA_g  = (const float*)d_in[8];
  const float* lnA_b  = (const float*)d_in[9];
  const float* Wq     = (const float*)d_in[10];
  const float* bq     = (const float*)d_in[11];
  const float* Wk     = (const float*)d_in[12];
  const float* bk     = (const float*)d_in[13];
  const float* Wv     = (const float*)d_in[14];
  const float* bv     = (const float*)d_in[15];
  const float* Wo     = (const float*)d_in[16];
  const float* bo     = (const float*)d_in[17];
  const float* Wpos   = (const float*)d_in[18];
  const float* pbu    = (const float*)d_in[19];
  const float* pbv    = (const float*)d_in[20];
  const float* lnC_g  = (const float*)d_in[21];
  const float* lnC_b  = (const float*)d_in[22];
  const float* pw1_w  = (const float*)d_in[23];
  const float* pw1_b  = (const float*)d_in[24];
  const float* dw_w   = (const float*)d_in[25];
  const float* dw_b   = (const float*)d_in[26];
  const float* cln_g  = (const float*)d_in[27];
  const float* cln_b  = (const float*)d_in[28];
  const float* pw2_w  = (const float*)d_in[29];
  const float* pw2_b  = (const float*)d_in[30];
  const float* ln2_g  = (const float*)d_in[31];
  const float* ln2_b  = (const float*)d_in[32];
  const float* ff2_w1 = (const float*)d_in[33];
  const float* ff2_b1 = (const float*)d_in[34];
  const float* ff2_w2 = (const float*)d_in[35];
  const float* ff2_b2 = (const float*)d_in[36];
  const float* lnO_g  = (const float*)d_in[37];
  const float* lnO_b  = (const float*)d_in[38];
  (void)in_sizes; (void)n_in; (void)out_size; (void)ws_size;

  char* ws = (char*)d_ws;
  size_t off = 0;
  auto alloc = [&](size_t bytes) -> void* {
    off = (off + 255) & ~(size_t)255;
    void* p = ws + off;
    off += bytes;
    return p;
  };

  // weights (bf16, [N,K] layout)
  u16* wt_ff1w1 = (u16*)alloc((size_t)CL * CDFF * CD * 2);
  u16* wt_ff1w2 = (u16*)alloc((size_t)CL * CD * CDFF * 2);
  u16* wt_qkv   = (u16*)alloc((size_t)CL * 1536 * CD * 2);
  u16* wt_o     = (u16*)alloc((size_t)CL * CD * CD * 2);
  u16* wt_pos   = (u16*)alloc((size_t)CL * CD * CD * 2);
  u16* w_pw1p   = (u16*)alloc((size_t)CL * 1024 * CD * 2);
  u16* w_pw2    = (u16*)alloc((size_t)CL * CD * CD * 2);
  u16* wt_ff2w1 = (u16*)alloc((size_t)CL * CDFF * CD * 2);
  u16* wt_ff2w2 = (u16*)alloc((size_t)CL * CD * CDFF * 2);
  float* qkvbias = (float*)alloc((size_t)CL * 1536 * 4);
  u16* posbf = (u16*)alloc((size_t)1024 * CD * 2);
  float* dwT = (float*)alloc((size_t)CL * 31 * CD * 4);
  u16* pbf_all = (u16*)alloc((size_t)1024 * 2048 * 2);
  // activations
  float* cur = (float*)alloc((size_t)CNBT * CD * 4);
  u16* ybf   = (u16*)alloc((size_t)CNBT * CD * 2);
  u16* qkv   = (u16*)alloc((size_t)CNBT * 1536 * 2);
  u16* hbf   = (u16*)alloc((size_t)CNBT * CDFF * 2);
  u16* vt    = (u16*)alloc((size_t)64 * CDK * CT * 2);
  u16* obf   = (u16*)alloc((size_t)CNBT * CD * 2);
  u16* ubuf  = (u16*)alloc((size_t)CNBT * CD * 2);
  u16* cbf   = (u16*)alloc((size_t)CNBT * CD * 2);

  dim3 b256(256);
  dim3 tb(32, 8);

  // ---- setup: weight conversion (every call; deterministic) ----
  tconv2x_k<<<dim3(CDFF / 32, CD / 32, 2 * CL), tb, 0, stream>>>(
      ff1_w1, ff2_w1, wt_ff1w1, wt_ff2w1, CD, CDFF);
  tconv2x_k<<<dim3(CD / 32, CDFF / 32, 2 * CL), tb, 0, stream>>>(
      ff1_w2, ff2_w2, wt_ff1w2, wt_ff2w2, CDFF, CD);
  tconvQ_k<<<dim3(CD / 32, CD / 32, 5 * CL), tb, 0, stream>>>(
      Wq, Wk, Wv, Wo, Wpos, wt_qkv, wt_o, wt_pos);
  pwperm_k<<<dim3(512, CL), b256, 0, stream>>>(pw1_w, w_pw1p);
  cvt_k<<<dim3(256, CL, 1), b256, 0, stream>>>(pw2_w, w_pw2, 512L * 512, 512L * 512,
                                               512L * 512, 512L * 512);
  setup3_k<<<dim3(512, 3), b256, 0, stream>>>(in_pos, posbf, dw_w, dwT,
                                              bq, bk, bv, qkvbias);
  ln_cp_k<<<dim3(1024), b256, 0, stream>>>(in_x, cur, ybf, ln1_g, ln1_b);
  // all-layer pos projection: pbf_all[j][l*512+c]
  gemm2_k<0, 1><<<dim3(16, 32, 1), b256, 0, stream>>>(
      posbf, wt_pos, pbf_all, nullptr, 0.f, CD, CD, 2048, CD);

  for (int i = 0; i < CL; ++i) {
    const u16* Wf1 = wt_ff1w1 + (long)i * CDFF * CD;
    const u16* Wf2 = wt_ff1w2 + (long)i * CD * CDFF;
    const u16* Wqk = wt_qkv + (long)i * 1536 * CD;
    const u16* Wou = wt_o + (long)i * CD * CD;
    const u16* Wp1 = w_pw1p + (long)i * 1024 * CD;
    const u16* Wp2 = w_pw2 + (long)i * CD * CD;
    const u16* Wf3 = wt_ff2w1 + (long)i * CDFF * CD;
    const u16* Wf4 = wt_ff2w2 + (long)i * CD * CDFF;

    // ---- FFN1 (half residual); ybf already = LN(cur; ln1) ----
    gemmB_k<2><<<dim3(32, 16, 1), b256, 0, stream>>>(
        ybf, Wf1, hbf, nullptr, ff1_b1 + (long)i * CDFF, CD, CD, CDFF, CD);
    gemm2_k<3, 1><<<dim3(64, 8, 1), b256, 0, stream>>>(
        hbf, Wf2, cur, ff1_b2 + i * CD, 0.5f, CDFF, CDFF, CD, CDFF);

    // ---- rel-pos MHSA (fused; V-transpose in QKV epilogue) ----
    ln_k<0><<<dim3(1024), b256, 0, stream>>>(cur, ybf, lnA_g + i * CD, lnA_b + i * CD);
    gemmB_k<8><<<dim3(32, 12, 1), b256, 0, stream>>>(
        ybf, Wqk, qkv, vt, qkvbias + i * 1536, CD, CD, 1536, CD);
    attn_k<<<dim3(8, 64), b256, 0, stream>>>(qkv, pbf_all + i * 512, pbu + i * 512,
                                             pbv + i * 512, vt, obf);
    gemm2_k<3, 1><<<dim3(64, 8, 1), b256, 0, stream>>>(
        obf, Wou, cur, bo + i * CD, 1.0f, CD, CD, CD, CD);

    // ---- conv module ----
    ln_k<0><<<dim3(1024), b256, 0, stream>>>(cur, ybf, lnC_g + i * CD, lnC_b + i * CD);
    gemmB_k<7><<<dim3(32, 8, 1), b256, 0, stream>>>(
        ybf, Wp1, ubuf, nullptr, pw1_b + (long)i * 1024, CD, CD, 512, CD);
    conv2_k<<<dim3(CT / 8, 8), b256, 0, stream>>>(ubuf, dwT + (long)i * 31 * CD,
                                                  dw_b + i * CD, cln_g + i * CD,
                                                  cln_b + i * CD, cbf);
    gemm2_k<3, 1><<<dim3(64, 8, 1), b256, 0, stream>>>(
        cbf, Wp2, cur, pw2_b + i * CD, 1.0f, CD, CD, CD, CD);

    // ---- FFN2 (half residual) ----
    ln_k<0><<<dim3(1024), b256, 0, stream>>>(cur, ybf, ln2_g + i * CD, ln2_b + i * CD);
    gemmB_k<2><<<dim3(32, 16, 1), b256, 0, stream>>>(
        ybf, Wf3, hbf, nullptr, ff2_b1 + (long)i * CDFF, CD, CD, CDFF, CD);
    gemm2_k<3, 1><<<dim3(64, 8, 1), b256, 0, stream>>>(
        hbf, Wf4, cur, ff2_b2 + i * CD, 0.5f, CDFF, CDFF, CD, CDFF);

    // ---- output LN (fused with next layer's ln1) ----
    if (i < CL - 1)
      lnln_k<<<dim3(1024), b256, 0, stream>>>(cur, ybf, lnO_g + i * CD, lnO_b + i * CD,
                                              ln1_g + (i + 1) * CD, ln1_b + (i + 1) * CD);
    else
      ln_k<1><<<dim3(1024), b256, 0, stream>>>(cur, d_out, lnO_g + i * CD, lnO_b + i * CD);
  }
}

// Round 12
// 757.415 us; speedup vs baseline: 1.0262x; 1.0262x over previous
//
#include <hip/hip_runtime.h>

// ---------------------------------------------------------------------------
// Conformer encoder, MI355X bf16-MFMA implementation.
// Round 11: REVERT GEMMs to the measured-best round-9 config (gemm2 3-buf
// 48KB + __syncthreads; gemmB BK=64 2-buf + T1 swizzle) — R10/R11 pipeline
// surgery was null. NEW: all 7 independent setup kernels merged into one
// setupall_k (flat-grid section decode) — 6 fewer serialized launches.
// ---------------------------------------------------------------------------

typedef unsigned short u16;
typedef unsigned int u32;
typedef __attribute__((ext_vector_type(8))) short bf16x8;
typedef __attribute__((ext_vector_type(4))) float f32x4;

#define DI __device__ __forceinline__

constexpr int CT = 512;     // sequence length T
constexpr int CD = 512;     // model dim D
constexpr int CH = 8;       // heads
constexpr int CDK = 64;     // head dim
constexpr int CDFF = 2048;  // ffn dim
constexpr int CNBT = 4096;  // B*T
constexpr int CL = 4;       // layers

DI u16 f2bf(float f) {
  u32 u = __builtin_bit_cast(u32, f);
  u = u + 0x7fffu + ((u >> 16) & 1u);
  return (u16)(u >> 16);
}
DI float bf2f(u16 h) { u32 u = ((u32)h) << 16; return __builtin_bit_cast(float, u); }
DI u32 pack2(float a, float b) { return (u32)f2bf(a) | ((u32)f2bf(b) << 16); }
DI float sigm(float x) { return 1.0f / (1.0f + __expf(-x)); }

DI f32x4 MFMA(bf16x8 a, bf16x8 b, f32x4 c) {
  return __builtin_amdgcn_mfma_f32_16x16x32_bf16(a, b, c, 0, 0, 0);
}

DI void gload16(const void* g, void* l) {
  __builtin_amdgcn_global_load_lds((const __attribute__((address_space(1))) void*)g,
                                   (__attribute__((address_space(3))) void*)l, 16, 0, 0);
}

DI float wsum(float v) {
#pragma unroll
  for (int o = 32; o > 0; o >>= 1) v += __shfl_xor(v, o, 64);
  return v;
}

// ------------------------- merged setup ------------------------------------
// 32x32 transpose tile helper body: in [R,C] f32 -> out [C,R] bf16
DI void tbody(const float* ip, u16* op, int R, int C, int c0, int r0,
              int tx, int ty) {
  __shared__ float t[32][33];
#pragma unroll
  for (int i = ty; i < 32; i += 8)
    t[i][tx] = ip[(long)(r0 + i) * C + c0 + tx];
  __syncthreads();
#pragma unroll
  for (int i = ty; i < 32; i += 8)
    op[(long)(c0 + i) * R + r0 + tx] = f2bf(t[tx][i]);
}

// All independent setup work in one launch. Flat grid, section decode:
// S0 [0,8192)      : transpose ff1_w1/ff2_w1 (R=512,C=2048)
// S1 [8192,16384)  : transpose ff1_w2/ff2_w2 (R=2048,C=512)
// S2 [16384,21504) : transpose Wq/Wk/Wv/Wo/Wpos (512x512, 5x4 slices)
// S3 [21504,23552) : pw1 permute (GLU interleave)
// S4 [23552,24576) : pw2 fp32->bf16
// S5 [24576,26112) : pos cvt / dw transpose / qkv bias pack
// S6 [26112,27136) : layer-0 copy + LN(ln1)
__global__ __launch_bounds__(256) void setupall_k(
    const float* __restrict__ ff1_w1, const float* __restrict__ ff2_w1,
    u16* __restrict__ wt_ff1w1, u16* __restrict__ wt_ff2w1,
    const float* __restrict__ ff1_w2, const float* __restrict__ ff2_w2,
    u16* __restrict__ wt_ff1w2, u16* __restrict__ wt_ff2w2,
    const float* __restrict__ Wq, const float* __restrict__ Wk,
    const float* __restrict__ Wv, const float* __restrict__ Wo,
    const float* __restrict__ Wpos, u16* __restrict__ wt_qkv,
    u16* __restrict__ wt_o, u16* __restrict__ wt_pos,
    const float* __restrict__ pw1_w, u16* __restrict__ w_pw1p,
    const float* __restrict__ pw2_w, u16* __restrict__ w_pw2,
    const float* __restrict__ in_pos, u16* __restrict__ posbf,
    const float* __restrict__ dw_w, float* __restrict__ dwT,
    const float* __restrict__ bq, const float* __restrict__ bk,
    const float* __restrict__ bv, float* __restrict__ qkvb,
    const float* __restrict__ in_x, float* __restrict__ cur,
    u16* __restrict__ ybf, const float* __restrict__ ln1_g,
    const float* __restrict__ ln1_b) {
  const long Bk = blockIdx.x;
  const int tx = threadIdx.x, ty = threadIdx.y;
  const int tid = ty * 32 + tx;
  if (Bk < 8192) {
    long b = Bk;
    int x = (int)(b & 63), y = (int)((b >> 6) & 15), z = (int)(b >> 10);
    int l = z & 3;
    const float* ip = (z < 4 ? ff1_w1 : ff2_w1) + (long)l * 512 * 2048;
    u16* op = (z < 4 ? wt_ff1w1 : wt_ff2w1) + (long)l * 512 * 2048;
    tbody(ip, op, 512, 2048, x * 32, y * 32, tx, ty);
  } else if (Bk < 16384) {
    long b = Bk - 8192;
    int x = (int)(b & 15), y = (int)((b >> 4) & 63), z = (int)(b >> 10);
    int l = z & 3;
    const float* ip = (z < 4 ? ff1_w2 : ff2_w2) + (long)l * 512 * 2048;
    u16* op = (z < 4 ? wt_ff1w2 : wt_ff2w2) + (long)l * 512 * 2048;
    tbody(ip, op, 2048, 512, x * 32, y * 32, tx, ty);
  } else if (Bk < 21504) {
    long b = Bk - 16384;
    int x = (int)(b & 15), y = (int)((b >> 4) & 15), z = (int)(b >> 8);
    int sel = z >> 2, l = z & 3;
    const float* ip;
    u16* op;
    const long S = 512L * 512;
    switch (sel) {
      case 0: ip = Wq + l * S; op = wt_qkv + (long)l * 1536 * 512; break;
      case 1: ip = Wk + l * S; op = wt_qkv + (long)l * 1536 * 512 + S; break;
      case 2: ip = Wv + l * S; op = wt_qkv + (long)l * 1536 * 512 + 2 * S; break;
      case 3: ip = Wo + l * S; op = wt_o + l * S; break;
      default: ip = Wpos + l * S; op = wt_pos + l * S; break;
    }
    tbody(ip, op, 512, 512, x * 32, y * 32, tx, ty);
  } else if (Bk < 23552) {
    long b = Bk - 21504;
    int x = (int)(b & 511), l = (int)(b >> 9);
    long i = (long)x * 256 + tid;
    long n = i >> 7;
    int c = (int)(i & 127) * 4;
    int q = (int)(n >> 4) & 1;
    long r = (q ? 512 : 0) + ((n >> 5) << 4) + (n & 15);
    const float* ip = pw1_w + ((long)l * 1024 + r) * 512 + c;
    float4 v = *(const float4*)ip;
    u16* op = w_pw1p + ((long)l * 1024 + n) * 512 + c;
    uint2 st;
    st.x = pack2(v.x, v.y);
    st.y = pack2(v.z, v.w);
    *(uint2*)op = st;
  } else if (Bk < 24576) {
    long b = Bk - 23552;
    int x = (int)(b & 255), l = (int)(b >> 8);
    long i = ((long)x * 256 + tid) * 4;
    const float* ip = pw2_w + (long)l * 512 * 512 + i;
    u16* op = w_pw2 + (long)l * 512 * 512 + i;
    float4 v = *(const float4*)ip;
    uint2 st;
    st.x = pack2(v.x, v.y);
    st.y = pack2(v.z, v.w);
    *(uint2*)op = st;
  } else if (Bk < 26112) {
    long b = Bk - 24576;
    int x = (int)(b & 511), y = (int)(b >> 9);
    if (y == 0) {
      long i = ((long)x * 256 + tid) * 4;
      const long nIn = 1023L * 512, nOut = 1024L * 512;
      if (i >= nOut) return;
      u16 o[4];
#pragma unroll
      for (int j = 0; j < 4; ++j) {
        long idx = i + j;
        o[j] = (idx < nIn) ? f2bf(in_pos[idx]) : (u16)0;
      }
      uint2 st;
      st.x = (u32)o[0] | ((u32)o[1] << 16);
      st.y = (u32)o[2] | ((u32)o[3] << 16);
      *(uint2*)&posbf[i] = st;
    } else if (y == 1) {
      long idx = (long)x * 256 + tid;
      if (idx >= 4L * 31 * 512) return;
      long l = idx / (31 * 512);
      int rem = (int)(idx % (31 * 512));
      int k = rem >> 9, d = rem & 511;
      dwT[idx] = dw_w[l * 512 * 31 + d * 31 + k];
    } else {
      long idx = (long)x * 256 + tid;
      if (idx >= 4L * 1536) return;
      int z = (int)(idx / 1536), j = (int)(idx % 1536);
      float v;
      if (j < 512) v = bq[z * 512 + j];
      else if (j < 1024) v = bk[z * 512 + j - 512];
      else v = bv[z * 512 + j - 1024];
      qkvb[idx] = v;
    }
  } else {
    long b = Bk - 26112;
    int wid = tid >> 6, lane = tid & 63;
    long row = b * 4 + wid;
    const float* x = in_x + row * CD + lane * 8;
    float v[8];
    *(float4*)&v[0] = *(const float4*)x;
    *(float4*)&v[4] = *(const float4*)(x + 4);
    float* cx = cur + row * CD + lane * 8;
    *(float4*)cx = *(float4*)&v[0];
    *(float4*)(cx + 4) = *(float4*)&v[4];
    float s = 0.f, q = 0.f;
#pragma unroll
    for (int j = 0; j < 8; ++j) { s += v[j]; q += v[j] * v[j]; }
    s = wsum(s);
    q = wsum(q);
    float mean = s * (1.0f / CD);
    float var = q * (1.0f / CD) - mean * mean;
    float rs = rsqrtf(var + 1e-5f);
    int c = lane * 8;
    float y[8];
#pragma unroll
    for (int j = 0; j < 8; ++j) y[j] = (v[j] - mean) * rs * ln1_g[c + j] + ln1_b[c + j];
    u16* o = ybf + row * CD + c;
    uint4 pk;
    pk.x = pack2(y[0], y[1]);
    pk.y = pack2(y[2], y[3]);
    pk.z = pack2(y[4], y[5]);
    pk.w = pack2(y[6], y[7]);
    *(uint4*)o = pk;
  }
}

// ------------------------------- LayerNorm ---------------------------------
template <int F32OUT>
__global__ __launch_bounds__(256) void ln_k(const float* in, void* out,
                                            const float* gw, const float* bw) {
  int tid = threadIdx.x, wid = tid >> 6, lane = tid & 63;
  long row = (long)blockIdx.x * 4 + wid;
  const float* x = in + row * CD + lane * 8;
  float4 v0 = *(const float4*)x;
  float4 v1 = *(const float4*)(x + 4);
  float s = v0.x + v0.y + v0.z + v0.w + v1.x + v1.y + v1.z + v1.w;
  float q = v0.x * v0.x + v0.y * v0.y + v0.z * v0.z + v0.w * v0.w +
            v1.x * v1.x + v1.y * v1.y + v1.z * v1.z + v1.w * v1.w;
  s = wsum(s);
  q = wsum(q);
  float mean = s * (1.0f / CD);
  float var = q * (1.0f / CD) - mean * mean;
  float rs = rsqrtf(var + 1e-5f);
  int c = lane * 8;
  float4 g0 = *(const float4*)(gw + c), g1 = *(const float4*)(gw + c + 4);
  float4 b0 = *(const float4*)(bw + c), b1 = *(const float4*)(bw + c + 4);
  float y0 = (v0.x - mean) * rs * g0.x + b0.x;
  float y1 = (v0.y - mean) * rs * g0.y + b0.y;
  float y2 = (v0.z - mean) * rs * g0.z + b0.z;
  float y3 = (v0.w - mean) * rs * g0.w + b0.w;
  float y4 = (v1.x - mean) * rs * g1.x + b1.x;
  float y5 = (v1.y - mean) * rs * g1.y + b1.y;
  float y6 = (v1.z - mean) * rs * g1.z + b1.z;
  float y7 = (v1.w - mean) * rs * g1.w + b1.w;
  if (F32OUT) {
    float* o = (float*)out + row * CD + c;
    *(float4*)o = make_float4(y0, y1, y2, y3);
    *(float4*)(o + 4) = make_float4(y4, y5, y6, y7);
  } else {
    u16* o = (u16*)out + row * CD + c;
    uint4 pk;
    pk.x = pack2(y0, y1);
    pk.y = pack2(y2, y3);
    pk.z = pack2(y4, y5);
    pk.w = pack2(y6, y7);
    *(uint4*)o = pk;
  }
}

// fused lnO (fp32 -> cur) + ln1-of-next-layer (bf16 -> ybf), one read pass
__global__ __launch_bounds__(256) void lnln_k(float* cur, u16* ybf,
                                              const float* gO, const float* bO,
                                              const float* g1, const float* b1) {
  int tid = threadIdx.x, wid = tid >> 6, lane = tid & 63;
  long row = (long)blockIdx.x * 4 + wid;
  float* x = cur + row * CD + lane * 8;
  float v[8];
  *(float4*)&v[0] = *(const float4*)x;
  *(float4*)&v[4] = *(const float4*)(x + 4);
  float s = 0.f, q = 0.f;
#pragma unroll
  for (int j = 0; j < 8; ++j) { s += v[j]; q += v[j] * v[j]; }
  s = wsum(s);
  q = wsum(q);
  float mean = s * (1.0f / CD);
  float var = q * (1.0f / CD) - mean * mean;
  float rs = rsqrtf(var + 1e-5f);
  int c = lane * 8;
  float y[8];
#pragma unroll
  for (int j = 0; j < 8; ++j) y[j] = (v[j] - mean) * rs * gO[c + j] + bO[c + j];
  *(float4*)x = *(float4*)&y[0];
  *(float4*)(x + 4) = *(float4*)&y[4];
  float s2 = 0.f, q2 = 0.f;
#pragma unroll
  for (int j = 0; j < 8; ++j) { s2 += y[j]; q2 += y[j] * y[j]; }
  s2 = wsum(s2);
  q2 = wsum(q2);
  float mean2 = s2 * (1.0f / CD);
  float var2 = q2 * (1.0f / CD) - mean2 * mean2;
  float rs2 = rsqrtf(var2 + 1e-5f);
  float z[8];
#pragma unroll
  for (int j = 0; j < 8; ++j) z[j] = (y[j] - mean2) * rs2 * g1[c + j] + b1[c + j];
  u16* o = ybf + row * CD + c;
  uint4 pk;
  pk.x = pack2(z[0], z[1]);
  pk.y = pack2(z[2], z[3]);
  pk.z = pack2(z[4], z[5]);
  pk.w = pack2(z[6], z[7]);
  *(uint4*)o = pk;
}

// --------------------------------- GEMM v2 (64x64) -------------------------
// Round-9 proven config: 3-buffer, vmcnt(4) + __syncthreads per K-tile.
// EPI: 0 store bf16 | 3 res += alpha*(v+bias)
template <int EPI, int SPLITK>
__global__ __launch_bounds__(256, 2) void gemm2_k(
    const u16* __restrict__ A, const u16* __restrict__ B, void* C,
    const float* __restrict__ bias, float alpha, int lda, int ldb, int ldc, int Kd) {
  __shared__ u16 lds[3][2][64 * 64];  // [buf][A/B][row*64]
  const int tid = threadIdx.x, wid = tid >> 6, lane = tid & 63;
  const int m0 = blockIdx.x * 64, n0 = blockIdx.y * 64;
  const int wm = wid >> 1, wn = wid & 1;
  const int fr = lane & 15, fq = lane >> 4;
  const f32x4 vz = {0.f, 0.f, 0.f, 0.f};
  f32x4 acc[2][2] = {{vz, vz}, {vz, vz}};

  const int Kc = Kd / SPLITK;
  const int kb0 = (SPLITK > 1) ? blockIdx.z * Kc : 0;
  const int nK = Kc / 64;

  auto stage = [&](int buf, int kt) {
    const int k0 = kb0 + kt * 64;
#pragma unroll
    for (int r = 0; r < 2; ++r) {
      int bi = r * 4096 + tid * 16;
      int row = bi >> 7;
      int ch = ((bi >> 4) & 7) ^ (row & 7);  // inverse swizzle on source
      gload16(A + (long)(m0 + row) * lda + k0 + ch * 8,
              (char*)&lds[buf][0][0] + r * 4096 + wid * 1024);
      gload16(B + (long)(n0 + row) * ldb + k0 + ch * 8,
              (char*)&lds[buf][1][0] + r * 4096 + wid * 1024);
    }
  };

  stage(0, 0);
  if (nK > 1) stage(1, 1);
  for (int kt = 0; kt < nK; ++kt) {
    const int buf = kt % 3;
    if (kt + 1 < nK)
      asm volatile("s_waitcnt vmcnt(4)" ::: "memory");
    else
      asm volatile("s_waitcnt vmcnt(0)" ::: "memory");
    __syncthreads();
    if (kt + 2 < nK) stage((kt + 2) % 3, kt + 2);
    bf16x8 af[2][2], bfv[2][2];
#pragma unroll
    for (int ks = 0; ks < 2; ++ks) {
      int ch = ks * 4 + fq;
#pragma unroll
      for (int i = 0; i < 2; ++i) {
        int arow = wm * 32 + i * 16 + fr;
        af[ks][i] = *(const bf16x8*)((const char*)&lds[buf][0][0] + arow * 128 +
                                     ((ch ^ (arow & 7)) << 4));
        int brow = wn * 32 + i * 16 + fr;
        bfv[ks][i] = *(const bf16x8*)((const char*)&lds[buf][1][0] + brow * 128 +
                                      ((ch ^ (brow & 7)) << 4));
      }
    }
#pragma unroll
    for (int ks = 0; ks < 2; ++ks)
#pragma unroll
      for (int mi = 0; mi < 2; ++mi)
#pragma unroll
        for (int ni = 0; ni < 2; ++ni)
          acc[mi][ni] = MFMA(af[ks][mi], bfv[ks][ni], acc[mi][ni]);
  }

#pragma unroll
  for (int mi = 0; mi < 2; ++mi) {
    const int gmB = m0 + wm * 32 + mi * 16 + fq * 4;
#pragma unroll
    for (int ni = 0; ni < 2; ++ni) {
      const int gn = n0 + wn * 32 + ni * 16 + fr;
      float bv_ = 0.f;
      if constexpr (EPI == 3) bv_ = bias[gn];
#pragma unroll
      for (int r = 0; r < 4; ++r) {
        const int gm = gmB + r;
        float v = acc[mi][ni][r];
        long idx = (long)gm * ldc + gn;
        if constexpr (EPI == 0) ((u16*)C)[idx] = f2bf(v);
        else if constexpr (EPI == 3) {
          float* R = (float*)C;
          if constexpr (SPLITK > 1) {
            float add = alpha * (v + (blockIdx.z == 0 ? bv_ : 0.f));
            atomicAdd(&R[idx], add);
          } else {
            R[idx] += alpha * (v + bv_);
          }
        }
      }
    }
  }
}

// --------------------------------- GEMM vB (128x128) -----------------------
// Round-9 proven config: BK=64, 2-buf, vmcnt(0)+__syncthreads per tile,
// XCD-bijective tile swizzle (T1; grid %8==0).
// EPI: 2 +bias swish | 7 GLU-packed | 8 qkv (+v-transpose to Caux)
template <int EPI>
__global__ __launch_bounds__(256, 2) void gemmB_k(
    const u16* __restrict__ A, const u16* __restrict__ B, void* C,
    u16* __restrict__ Caux, const float* __restrict__ bias,
    int lda, int ldb, int ldc, int Kd) {
  __shared__ u16 ldsA[2][128 * 64];
  __shared__ u16 ldsB[2][128 * 64];
  const int tid = threadIdx.x, wid = tid >> 6, lane = tid & 63;
  const int nwg = gridDim.x * gridDim.y;
  int lin = blockIdx.y * gridDim.x + blockIdx.x;
  lin = (lin & 7) * (nwg >> 3) + (lin >> 3);
  const int m0 = (lin % gridDim.x) * 128, n0 = (lin / gridDim.x) * 128;
  const int wm = wid >> 1, wn = wid & 1;
  const int fr = lane & 15, fq = lane >> 4;
  const f32x4 vz = {0.f, 0.f, 0.f, 0.f};
  f32x4 acc[4][4];
#pragma unroll
  for (int mi = 0; mi < 4; ++mi)
#pragma unroll
    for (int ni = 0; ni < 4; ++ni) acc[mi][ni] = vz;
  const int nK = Kd / 64;

  auto stage = [&](int buf, int kt) {
    const int k0 = kt * 64;
#pragma unroll
    for (int r = 0; r < 4; ++r) {
      int bi = r * 4096 + tid * 16;
      int row = bi >> 7;  // 128 B per 64-elem bf16 row
      int ch = ((bi >> 4) & 7) ^ (row & 7);
      gload16(A + (long)(m0 + row) * lda + k0 + ch * 8,
              (char*)&ldsA[buf][0] + r * 4096 + wid * 1024);
      gload16(B + (long)(n0 + row) * ldb + k0 + ch * 8,
              (char*)&ldsB[buf][0] + r * 4096 + wid * 1024);
    }
  };

  stage(0, 0);
  asm volatile("s_waitcnt vmcnt(0)" ::: "memory");
  __syncthreads();
  int buf = 0;
  for (int kt = 0; kt < nK; ++kt) {
    if (kt + 1 < nK) stage(buf ^ 1, kt + 1);
#pragma unroll
    for (int ks = 0; ks < 2; ++ks) {
      int ch = ks * 4 + fq;
      bf16x8 af[4], bfv[4];
#pragma unroll
      for (int i = 0; i < 4; ++i) {
        int arow = wm * 64 + i * 16 + fr;
        af[i] = *(const bf16x8*)((const char*)&ldsA[buf][0] + arow * 128 +
                                 ((ch ^ (arow & 7)) << 4));
        int brow = wn * 64 + i * 16 + fr;
        bfv[i] = *(const bf16x8*)((const char*)&ldsB[buf][0] + brow * 128 +
                                  ((ch ^ (brow & 7)) << 4));
      }
#pragma unroll
      for (int mi = 0; mi < 4; ++mi)
#pragma unroll
        for (int ni = 0; ni < 4; ++ni)
          acc[mi][ni] = MFMA(af[mi], bfv[ni], acc[mi][ni]);
    }
    asm volatile("s_waitcnt vmcnt(0)" ::: "memory");
    __syncthreads();
    buf ^= 1;
  }

  if constexpr (EPI == 2) {
#pragma unroll
    for (int mi = 0; mi < 4; ++mi) {
      const int gmB = m0 + wm * 64 + mi * 16 + fq * 4;
#pragma unroll
      for (int ni = 0; ni < 4; ++ni) {
        const int gn = n0 + wn * 64 + ni * 16 + fr;
        float bv_ = bias[gn];
#pragma unroll
        for (int r = 0; r < 4; ++r) {
          float x = acc[mi][ni][r] + bv_;
          ((u16*)C)[(long)(gmB + r) * ldc + gn] = f2bf(x * sigm(x));
        }
      }
    }
  } else if constexpr (EPI == 7) {
#pragma unroll
    for (int mi = 0; mi < 4; ++mi) {
      const int gmB = m0 + wm * 64 + mi * 16 + fq * 4;
#pragma unroll
      for (int p = 0; p < 2; ++p) {
        const int ucol = (n0 >> 1) + wn * 32 + p * 16 + fr;
        float ba = bias[ucol], bg = bias[512 + ucol];
#pragma unroll
        for (int r = 0; r < 4; ++r) {
          float va = acc[mi][2 * p][r] + ba;
          float vg = acc[mi][2 * p + 1][r] + bg;
          ((u16*)C)[(long)(gmB + r) * 512 + ucol] = f2bf(va * sigm(vg));
        }
      }
    }
  } else if constexpr (EPI == 8) {
    if (n0 < 1024) {
#pragma unroll
      for (int mi = 0; mi < 4; ++mi) {
        const int gmB = m0 + wm * 64 + mi * 16 + fq * 4;
#pragma unroll
        for (int ni = 0; ni < 4; ++ni) {
          const int gn = n0 + wn * 64 + ni * 16 + fr;
          float bv_ = bias[gn];
#pragma unroll
          for (int r = 0; r < 4; ++r)
            ((u16*)C)[(long)(gmB + r) * ldc + gn] = f2bf(acc[mi][ni][r] + bv_);
        }
      }
    } else {
#pragma unroll
      for (int mi = 0; mi < 4; ++mi) {
        const int gmB = m0 + wm * 64 + mi * 16 + fq * 4;
        const int b = gmB >> 9, t = gmB & 511;
#pragma unroll
        for (int ni = 0; ni < 4; ++ni) {
          const int gn = n0 + wn * 64 + ni * 16 + fr;
          const int h = (gn - 1024) >> 6, d = (gn - 1024) & 63;
          float bv_ = bias[gn];
          uint2 pk;
          pk.x = pack2(acc[mi][ni][0] + bv_, acc[mi][ni][1] + bv_);
          pk.y = pack2(acc[mi][ni][2] + bv_, acc[mi][ni][3] + bv_);
          *(uint2*)&Caux[((long)(b * 8 + h) * 64 + d) * 512 + t] = pk;
        }
      }
    }
  }
}

// ---------------- fused rel-pos flash attention v2 -------------------------
__global__ __launch_bounds__(256, 2) void attn_k(
    const u16* __restrict__ qkvp, const u16* __restrict__ pball,
    const float* __restrict__ pbuL, const float* __restrict__ pbvL,
    const u16* __restrict__ vt, u16* __restrict__ out) {
  __shared__ u16 ldsK[2][64 * 64];    // [s][d] swizzled
  __shared__ u16 ldsP[2][128 * 64];   // [j][d] swizzled
  __shared__ u16 bd0s[4][16 * 80];    // per-wave bd band
  __shared__ u16 stile[4][16 * 64];   // per-wave P (swizzled rows)
  const int tid = threadIdx.x, wid = tid >> 6, lane = tid & 63;
  const int t0 = blockIdx.x * 64;
  const int bh = blockIdx.y, b = bh >> 3, h = bh & 7;
  const int fr = lane & 15, fq = lane >> 4;

  const u16* kbase = qkvp + (long)(b * CT) * 1536 + 512 + h * 64;
  const u16* pbase = pball + h * 64;
  const float* pu = pbuL + h * 64;
  const float* pv = pbvL + h * 64;

  const u16* qp = qkvp + (long)(b * CT + t0 + wid * 16 + fr) * 1536 + h * 64;
  bf16x8 qua[2], qva[2];
#pragma unroll
  for (int kk = 0; kk < 2; ++kk) {
    bf16x8 qw = *(const bf16x8*)(qp + kk * 32 + fq * 8);
    const float* bu = pu + kk * 32 + fq * 8;
    const float* bv = pv + kk * 32 + fq * 8;
#pragma unroll
    for (int j = 0; j < 8; ++j) {
      float qf = bf2f((u16)qw[j]);
      qua[kk][j] = (short)f2bf(qf + bu[j]);
      qva[kk][j] = (short)f2bf(qf + bv[j]);
    }
  }

  const f32x4 vz = {0.f, 0.f, 0.f, 0.f};
  f32x4 oacc[4] = {vz, vz, vz, vz};
  float m_run[4] = {-1e30f, -1e30f, -1e30f, -1e30f};
  float l_run[4] = {0.f, 0.f, 0.f, 0.f};
  const int jbw = (3 - wid) * 16;

  auto stage = [&](int buf, int st) {
    int s0 = st * 64, j0 = s0 - t0 + 448;
#pragma unroll
    for (int r = 0; r < 2; ++r) {
      int c = r * 256 + tid;
      int row = c >> 3, cs = (c & 7) ^ (row & 7);
      gload16(kbase + (long)(s0 + row) * 1536 + cs * 8,
              (char*)&ldsK[buf][0] + r * 4096 + wid * 1024);
    }
#pragma unroll
    for (int r = 0; r < 4; ++r) {
      int c = r * 256 + tid;
      int row = c >> 3, cs = (c & 7) ^ (row & 7);
      gload16(pbase + (long)(j0 + row) * 2048 + cs * 8,
              (char*)&ldsP[buf][0] + r * 4096 + wid * 1024);
    }
  };

  stage(0, 0);
  int cur = 0;
  for (int st = 0; st < 8; ++st) {
    const int s0 = st * 64;
    if (st + 1 < 8) {
      stage(cur ^ 1, st + 1);
      asm volatile("s_waitcnt vmcnt(6)" ::: "memory");
    } else {
      asm volatile("s_waitcnt vmcnt(0)" ::: "memory");
    }
    __syncthreads();

    bf16x8 vb[4][2];
#pragma unroll
    for (int ni = 0; ni < 4; ++ni)
#pragma unroll
      for (int kk = 0; kk < 2; ++kk)
        vb[ni][kk] = *(const bf16x8*)&vt[((long)bh * 64 + ni * 16 + fr) * 512 +
                                         s0 + kk * 32 + fq * 8];

    __builtin_amdgcn_s_setprio(1);
    f32x4 ac[4] = {vz, vz, vz, vz};
#pragma unroll
    for (int kk = 0; kk < 2; ++kk) {
#pragma unroll
      for (int ni = 0; ni < 4; ++ni) {
        int row = ni * 16 + fr;
        bf16x8 kb = *(const bf16x8*)((const char*)&ldsK[cur][0] +
                                     ((row * 128 + kk * 64 + fq * 16) ^ ((row & 7) << 4)));
        ac[ni] = MFMA(qua[kk], kb, ac[ni]);
      }
    }
    f32x4 bd[5] = {vz, vz, vz, vz, vz};
#pragma unroll
    for (int kk = 0; kk < 2; ++kk) {
#pragma unroll
      for (int nbi = 0; nbi < 5; ++nbi) {
        int row = jbw + nbi * 16 + fr;
        bf16x8 pb = *(const bf16x8*)((const char*)&ldsP[cur][0] +
                                     ((row * 128 + kk * 64 + fq * 16) ^ ((row & 7) << 4)));
        bd[nbi] = MFMA(qva[kk], pb, bd[nbi]);
      }
    }
    __builtin_amdgcn_s_setprio(0);
#pragma unroll
    for (int nbi = 0; nbi < 5; ++nbi)
#pragma unroll
      for (int r = 0; r < 4; ++r)
        bd0s[wid][(fq * 4 + r) * 80 + nbi * 16 + fr] = f2bf(bd[nbi][r]);

    float vals[4][4];
#pragma unroll
    for (int ni = 0; ni < 4; ++ni)
#pragma unroll
      for (int r = 0; r < 4; ++r) {
        int tlw = fq * 4 + r;
        int jcol = ni * 16 + fr + 15 - tlw;
        vals[ni][r] = (ac[ni][r] + bf2f(bd0s[wid][tlw * 80 + jcol])) * 0.125f;
      }
    float scf[4];
#pragma unroll
    for (int r = 0; r < 4; ++r) {
      float mx = fmaxf(fmaxf(vals[0][r], vals[1][r]), fmaxf(vals[2][r], vals[3][r]));
      mx = fmaxf(mx, __shfl_xor(mx, 1));
      mx = fmaxf(mx, __shfl_xor(mx, 2));
      mx = fmaxf(mx, __shfl_xor(mx, 4));
      mx = fmaxf(mx, __shfl_xor(mx, 8));
      float mnew = fmaxf(m_run[r], mx);
      scf[r] = __expf(m_run[r] - mnew);
      m_run[r] = mnew;
      float sum = 0.f;
#pragma unroll
      for (int ni = 0; ni < 4; ++ni) {
        float p = __expf(vals[ni][r] - mnew);
        vals[ni][r] = p;
        sum += p;
      }
      sum += __shfl_xor(sum, 1);
      sum += __shfl_xor(sum, 2);
      sum += __shfl_xor(sum, 4);
      sum += __shfl_xor(sum, 8);
      l_run[r] = l_run[r] * scf[r] + sum;
    }
#pragma unroll
    for (int ni = 0; ni < 4; ++ni)
#pragma unroll
      for (int r = 0; r < 4; ++r) {
        int tlw = fq * 4 + r;
        *(u16*)((char*)&stile[wid][0] +
                (((tlw * 128) + (ni * 16 + fr) * 2) ^ ((tlw & 7) << 4))) =
            f2bf(vals[ni][r]);
      }
#pragma unroll
    for (int ni = 0; ni < 4; ++ni)
#pragma unroll
      for (int r = 0; r < 4; ++r) oacc[ni][r] *= scf[r];
    __builtin_amdgcn_s_setprio(1);
#pragma unroll
    for (int kk = 0; kk < 2; ++kk) {
      bf16x8 pa = *(const bf16x8*)((const char*)&stile[wid][0] +
                                   ((fr * 128 + kk * 64 + fq * 16) ^ ((fr & 7) << 4)));
#pragma unroll
      for (int ni = 0; ni < 4; ++ni) oacc[ni] = MFMA(pa, vb[ni][kk], oacc[ni]);
    }
    __builtin_amdgcn_s_setprio(0);
    __syncthreads();
    cur ^= 1;
  }

  float inv[4];
#pragma unroll
  for (int r = 0; r < 4; ++r) inv[r] = 1.0f / l_run[r];
#pragma unroll
  for (int ni = 0; ni < 4; ++ni)
#pragma unroll
    for (int r = 0; r < 4; ++r) {
      long row = (long)(b * CT + t0 + wid * 16 + fq * 4 + r) * CD + h * CDK;
      out[row + ni * 16 + fr] = f2bf(oacc[ni][r] * inv[r]);
    }
}

// ------------------------------ conv module --------------------------------
// depthwise conv(K=31,pad 15) + dw_b + LN(cln) + swish.
__global__ __launch_bounds__(256) void conv2_k(const u16* __restrict__ u,
                                               const float* __restrict__ wT,
                                               const float* __restrict__ wb,
                                               const float* __restrict__ cg,
                                               const float* __restrict__ cb,
                                               u16* __restrict__ out) {
  constexpr int TT = 8;
  int tid = threadIdx.x, d0 = tid * 2;
  int b = blockIdx.y, t0 = blockIdx.x * TT;
  const u16* ub = u + ((long)b * CT) * CD + d0;

  u32 strip[TT + 30];
#pragma unroll
  for (int j = 0; j < TT + 30; ++j) {
    int tt = t0 + j - 15;
    strip[j] = ((unsigned)tt < (unsigned)CT) ? *(const u32*)(ub + (long)tt * CD) : 0u;
  }
  float2 bias = *(const float2*)(wb + d0);
  float a0[TT], a1[TT];
#pragma unroll
  for (int t = 0; t < TT; ++t) { a0[t] = bias.x; a1[t] = bias.y; }
#pragma unroll
  for (int k = 0; k < 31; ++k) {
    float2 wk = *(const float2*)(wT + k * CD + d0);
#pragma unroll
    for (int t = 0; t < TT; ++t) {
      u32 pr = strip[t + k];
      a0[t] += bf2f((u16)(pr & 0xffff)) * wk.x;
      a1[t] += bf2f((u16)(pr >> 16)) * wk.y;
    }
  }
  __shared__ float redS[4][TT], redQ[4][TT];
  int wid = tid >> 6, lane = tid & 63;
#pragma unroll
  for (int t = 0; t < TT; ++t) {
    float s = a0[t] + a1[t];
    float q = a0[t] * a0[t] + a1[t] * a1[t];
    s = wsum(s);
    q = wsum(q);
    if (lane == 0) { redS[wid][t] = s; redQ[wid][t] = q; }
  }
  __syncthreads();
  float2 g2 = *(const float2*)(cg + d0);
  float2 b2 = *(const float2*)(cb + d0);
#pragma unroll
  for (int t = 0; t < TT; ++t) {
    float s = redS[0][t] + redS[1][t] + redS[2][t] + redS[3][t];
    float q = redQ[0][t] + redQ[1][t] + redQ[2][t] + redQ[3][t];
    float mean = s * (1.f / 512), var = q * (1.f / 512) - mean * mean;
    float rs = rsqrtf(var + 1e-5f);
    float y0 = (a0[t] - mean) * rs * g2.x + b2.x;
    float y1 = (a1[t] - mean) * rs * g2.y + b2.y;
    y0 = y0 * sigm(y0);
    y1 = y1 * sigm(y1);
    *(u32*)(out + ((long)(b * CT + t0 + t)) * CD + d0) = pack2(y0, y1);
  }
}

// ---------------------------------------------------------------------------
extern "C" void kernel_launch(void* const* d_in, const int* in_sizes, int n_in,
                              void* d_out, int out_size, void* d_ws, size_t ws_size,
                              hipStream_t stream) {
  const float* in_x   = (const float*)d_in[0];
  const float* in_pos = (const float*)d_in[1];
  const float* ln1_g  = (const float*)d_in[2];
  const float* ln1_b  = (const float*)d_in[3];
  const float* ff1_w1 = (const float*)d_in[4];
  const float* ff1_b1 = (const float*)d_in[5];
  const float* ff1_w2 = (const float*)d_in[6];
  const float* ff1_b2 = (const float*)d_in[7];
  const float* lnA_g  = (const float*)d_in[8];
  const float* lnA_b  = (const float*)d_in[9];
  const float* Wq     = (const float*)d_in[10];
  const float* bq     = (const float*)d_in[11];
  const float* Wk     = (const float*)d_in[12];
  const float* bk     = (const float*)d_in[13];
  const float* Wv     = (const float*)d_in[14];
  const float* bv     = (const float*)d_in[15];
  const float* Wo     = (const float*)d_in[16];
  const float* bo     = (const float*)d_in[17];
  const float* Wpos   = (const float*)d_in[18];
  const float* pbu    = (const float*)d_in[19];
  const float* pbv    = (const float*)d_in[20];
  const float* lnC_g  = (const float*)d_in[21];
  const float* lnC_b  = (const float*)d_in[22];
  const float* pw1_w  = (const float*)d_in[23];
  const float* pw1_b  = (const float*)d_in[24];
  const float* dw_w   = (const float*)d_in[25];
  const float* dw_b   = (const float*)d_in[26];
  const float* cln_g  = (const float*)d_in[27];
  const float* cln_b  = (const float*)d_in[28];
  const float* pw2_w  = (const float*)d_in[29];
  const float* pw2_b  = (const float*)d_in[30];
  const float* ln2_g  = (const float*)d_in[31];
  const float* ln2_b  = (const float*)d_in[32];
  const float* ff2_w1 = (const float*)d_in[33];
  const float* ff2_b1 = (const float*)d_in[34];
  const float* ff2_w2 = (const float*)d_in[35];
  const float* ff2_b2 = (const float*)d_in[36];
  const float* lnO_g  = (const float*)d_in[37];
  const float* lnO_b  = (const float*)d_in[38];
  (void)in_sizes; (void)n_in; (void)out_size; (void)ws_size;

  char* ws = (char*)d_ws;
  size_t off = 0;
  auto alloc = [&](size_t bytes) -> void* {
    off = (off + 255) & ~(size_t)255;
    void* p = ws + off;
    off += bytes;
    return p;
  };

  // weights (bf16, [N,K] layout)
  u16* wt_ff1w1 = (u16*)alloc((size_t)CL * CDFF * CD * 2);
  u16* wt_ff1w2 = (u16*)alloc((size_t)CL * CD * CDFF * 2);
  u16* wt_qkv   = (u16*)alloc((size_t)CL * 1536 * CD * 2);
  u16* wt_o     = (u16*)alloc((size_t)CL * CD * CD * 2);
  u16* wt_pos   = (u16*)alloc((size_t)CL * CD * CD * 2);
  u16* w_pw1p   = (u16*)alloc((size_t)CL * 1024 * CD * 2);
  u16* w_pw2    = (u16*)alloc((size_t)CL * CD * CD * 2);
  u16* wt_ff2w1 = (u16*)alloc((size_t)CL * CDFF * CD * 2);
  u16* wt_ff2w2 = (u16*)alloc((size_t)CL * CD * CDFF * 2);
  float* qkvbias = (float*)alloc((size_t)CL * 1536 * 4);
  u16* posbf = (u16*)alloc((size_t)1024 * CD * 2);
  float* dwT = (float*)alloc((size_t)CL * 31 * CD * 4);
  u16* pbf_all = (u16*)alloc((size_t)1024 * 2048 * 2);
  // activations
  float* cur = (float*)alloc((size_t)CNBT * CD * 4);
  u16* ybf   = (u16*)alloc((size_t)CNBT * CD * 2);
  u16* qkv   = (u16*)alloc((size_t)CNBT * 1536 * 2);
  u16* hbf   = (u16*)alloc((size_t)CNBT * CDFF * 2);
  u16* vt    = (u16*)alloc((size_t)64 * CDK * CT * 2);
  u16* obf   = (u16*)alloc((size_t)CNBT * CD * 2);
  u16* ubuf  = (u16*)alloc((size_t)CNBT * CD * 2);
  u16* cbf   = (u16*)alloc((size_t)CNBT * CD * 2);

  dim3 b256(256);
  dim3 tb(32, 8);

  // ---- setup: single merged kernel (weights, pos, biases, layer-0 LN) ----
  setupall_k<<<dim3(27136), tb, 0, stream>>>(
      ff1_w1, ff2_w1, wt_ff1w1, wt_ff2w1,
      ff1_w2, ff2_w2, wt_ff1w2, wt_ff2w2,
      Wq, Wk, Wv, Wo, Wpos, wt_qkv, wt_o, wt_pos,
      pw1_w, w_pw1p, pw2_w, w_pw2,
      in_pos, posbf, dw_w, dwT,
      bq, bk, bv, qkvbias,
      in_x, cur, ybf, ln1_g, ln1_b);
  // all-layer pos projection: pbf_all[j][l*512+c]
  gemm2_k<0, 1><<<dim3(16, 32, 1), b256, 0, stream>>>(
      posbf, wt_pos, pbf_all, nullptr, 0.f, CD, CD, 2048, CD);

  for (int i = 0; i < CL; ++i) {
    const u16* Wf1 = wt_ff1w1 + (long)i * CDFF * CD;
    const u16* Wf2 = wt_ff1w2 + (long)i * CD * CDFF;
    const u16* Wqk = wt_qkv + (long)i * 1536 * CD;
    const u16* Wou = wt_o + (long)i * CD * CD;
    const u16* Wp1 = w_pw1p + (long)i * 1024 * CD;
    const u16* Wp2 = w_pw2 + (long)i * CD * CD;
    const u16* Wf3 = wt_ff2w1 + (long)i * CDFF * CD;
    const u16* Wf4 = wt_ff2w2 + (long)i * CD * CDFF;

    // ---- FFN1 (half residual); ybf already = LN(cur; ln1) ----
    gemmB_k<2><<<dim3(32, 16, 1), b256, 0, stream>>>(
        ybf, Wf1, hbf, nullptr, ff1_b1 + (long)i * CDFF, CD, CD, CDFF, CD);
    gemm2_k<3, 1><<<dim3(64, 8, 1), b256, 0, stream>>>(
        hbf, Wf2, cur, ff1_b2 + i * CD, 0.5f, CDFF, CDFF, CD, CDFF);

    // ---- rel-pos MHSA (fused; V-transpose in QKV epilogue) ----
    ln_k<0><<<dim3(1024), b256, 0, stream>>>(cur, ybf, lnA_g + i * CD, lnA_b + i * CD);
    gemmB_k<8><<<dim3(32, 12, 1), b256, 0, stream>>>(
        ybf, Wqk, qkv, vt, qkvbias + i * 1536, CD, CD, 1536, CD);
    attn_k<<<dim3(8, 64), b256, 0, stream>>>(qkv, pbf_all + i * 512, pbu + i * 512,
                                             pbv + i * 512, vt, obf);
    gemm2_k<3, 1><<<dim3(64, 8, 1), b256, 0, stream>>>(
        obf, Wou, cur, bo + i * CD, 1.0f, CD, CD, CD, CD);

    // ---- conv module ----
    ln_k<0><<<dim3(1024), b256, 0, stream>>>(cur, ybf, lnC_g + i * CD, lnC_b + i * CD);
    gemmB_k<7><<<dim3(32, 8, 1), b256, 0, stream>>>(
        ybf, Wp1, ubuf, nullptr, pw1_b + (long)i * 1024, CD, CD, 512, CD);
    conv2_k<<<dim3(CT / 8, 8), b256, 0, stream>>>(ubuf, dwT + (long)i * 31 * CD,
                                                  dw_b + i * CD, cln_g + i * CD,
                                                  cln_b + i * CD, cbf);
    gemm2_k<3, 1><<<dim3(64, 8, 1), b256, 0, stream>>>(
        cbf, Wp2, cur, pw2_b + i * CD, 1.0f, CD, CD, CD, CD);

    // ---- FFN2 (half residual) ----
    ln_k<0><<<dim3(1024), b256, 0, stream>>>(cur, ybf, ln2_g + i * CD, ln2_b + i * CD);
    gemmB_k<2><<<dim3(32, 16, 1), b256, 0, stream>>>(
        ybf, Wf3, hbf, nullptr, ff2_b1 + (long)i * CDFF, CD, CD, CDFF, CD);
    gemm2_k<3, 1><<<dim3(64, 8, 1), b256, 0, stream>>>(
        hbf, Wf4, cur, ff2_b2 + i * CD, 0.5f, CDFF, CDFF, CD, CDFF);

    // ---- output LN (fused with next layer's ln1) ----
    if (i < CL - 1)
      lnln_k<<<dim3(1024), b256, 0, stream>>>(cur, ybf, lnO_g + i * CD, lnO_b + i * CD,
                                              ln1_g + (i + 1) * CD, ln1_b + (i + 1) * CD);
    else
      ln_k<1><<<dim3(1024), b256, 0, stream>>>(cur, d_out, lnO_g + i * CD, lnO_b + i * CD);
  }
}

// Round 13
// 752.484 us; speedup vs baseline: 1.0330x; 1.0066x over previous
//
#include <hip/hip_runtime.h>

// ---------------------------------------------------------------------------
// Conformer encoder, MI355X bf16-MFMA implementation.
// Round 12: setupall_k transpose sections rewritten as 64x64 tiles with
// float4 reads + uint4 (8x bf16) writes (was 32 scalar u16 stores/thread,
// 26% HBM). Everything else identical to the 757us round-11 config.
// ---------------------------------------------------------------------------

typedef unsigned short u16;
typedef unsigned int u32;
typedef __attribute__((ext_vector_type(8))) short bf16x8;
typedef __attribute__((ext_vector_type(4))) float f32x4;

#define DI __device__ __forceinline__

constexpr int CT = 512;     // sequence length T
constexpr int CD = 512;     // model dim D
constexpr int CH = 8;       // heads
constexpr int CDK = 64;     // head dim
constexpr int CDFF = 2048;  // ffn dim
constexpr int CNBT = 4096;  // B*T
constexpr int CL = 4;       // layers

DI u16 f2bf(float f) {
  u32 u = __builtin_bit_cast(u32, f);
  u = u + 0x7fffu + ((u >> 16) & 1u);
  return (u16)(u >> 16);
}
DI float bf2f(u16 h) { u32 u = ((u32)h) << 16; return __builtin_bit_cast(float, u); }
DI u32 pack2(float a, float b) { return (u32)f2bf(a) | ((u32)f2bf(b) << 16); }
DI float sigm(float x) { return 1.0f / (1.0f + __expf(-x)); }

DI f32x4 MFMA(bf16x8 a, bf16x8 b, f32x4 c) {
  return __builtin_amdgcn_mfma_f32_16x16x32_bf16(a, b, c, 0, 0, 0);
}

DI void gload16(const void* g, void* l) {
  __builtin_amdgcn_global_load_lds((const __attribute__((address_space(1))) void*)g,
                                   (__attribute__((address_space(3))) void*)l, 16, 0, 0);
}

DI float wsum(float v) {
#pragma unroll
  for (int o = 32; o > 0; o >>= 1) v += __shfl_xor(v, o, 64);
  return v;
}

// ------------------------- merged setup ------------------------------------
// 64x64 transpose tile: in [R,C] f32 -> out [C,R] bf16, vectorized I/O.
// Read: float4 per thread x4 (coalesced 256B). Stage t[64][65] (2-way bank
// alias on transposed read = free). Write: uint4 = 8 bf16 per thread x2
// (128B contiguous per 8 lanes).
DI void tbody64(const float* ip, u16* op, int R, int C, int c0, int r0,
                int tid) {
  __shared__ float t[64][65];
  const int rr = tid >> 4;          // 0..15
  const int cc = (tid & 15) * 4;    // 0..60
#pragma unroll
  for (int i = 0; i < 4; ++i) {
    float4 v = *(const float4*)(ip + (long)(r0 + rr + i * 16) * C + c0 + cc);
    t[rr + i * 16][cc] = v.x;
    t[rr + i * 16][cc + 1] = v.y;
    t[rr + i * 16][cc + 2] = v.z;
    t[rr + i * 16][cc + 3] = v.w;
  }
  __syncthreads();
  const int oc = tid >> 3;          // 0..31 (output row within tile)
  const int ork = (tid & 7) * 8;    // 0..56 (output col chunk)
#pragma unroll
  for (int i = 0; i < 2; ++i) {
    int row = oc + i * 32;
    u16 tmp[8];
#pragma unroll
    for (int j = 0; j < 8; ++j) tmp[j] = f2bf(t[ork + j][row]);
    uint4 pk;
    pk.x = (u32)tmp[0] | ((u32)tmp[1] << 16);
    pk.y = (u32)tmp[2] | ((u32)tmp[3] << 16);
    pk.z = (u32)tmp[4] | ((u32)tmp[5] << 16);
    pk.w = (u32)tmp[6] | ((u32)tmp[7] << 16);
    *(uint4*)(op + (long)(c0 + row) * R + r0 + ork) = pk;
  }
}

// All independent setup work in one launch. Flat grid, section decode:
// S0 [0,2048)     : transpose ff1_w1/ff2_w1 (R=512,C=2048), 64x64 tiles
// S1 [2048,4096)  : transpose ff1_w2/ff2_w2 (R=2048,C=512)
// S2 [4096,5376)  : transpose Wq/Wk/Wv/Wo/Wpos (512x512, 5x4 slices)
// S3 [5376,7424)  : pw1 permute (GLU interleave)
// S4 [7424,8448)  : pw2 fp32->bf16
// S5 [8448,9984)  : pos cvt / dw transpose / qkv bias pack
// S6 [9984,11008) : layer-0 copy + LN(ln1)
__global__ __launch_bounds__(256) void setupall_k(
    const float* __restrict__ ff1_w1, const float* __restrict__ ff2_w1,
    u16* __restrict__ wt_ff1w1, u16* __restrict__ wt_ff2w1,
    const float* __restrict__ ff1_w2, const float* __restrict__ ff2_w2,
    u16* __restrict__ wt_ff1w2, u16* __restrict__ wt_ff2w2,
    const float* __restrict__ Wq, const float* __restrict__ Wk,
    const float* __restrict__ Wv, const float* __restrict__ Wo,
    const float* __restrict__ Wpos, u16* __restrict__ wt_qkv,
    u16* __restrict__ wt_o, u16* __restrict__ wt_pos,
    const float* __restrict__ pw1_w, u16* __restrict__ w_pw1p,
    const float* __restrict__ pw2_w, u16* __restrict__ w_pw2,
    const float* __restrict__ in_pos, u16* __restrict__ posbf,
    const float* __restrict__ dw_w, float* __restrict__ dwT,
    const float* __restrict__ bq, const float* __restrict__ bk,
    const float* __restrict__ bv, float* __restrict__ qkvb,
    const float* __restrict__ in_x, float* __restrict__ cur,
    u16* __restrict__ ybf, const float* __restrict__ ln1_g,
    const float* __restrict__ ln1_b) {
  const long Bk = blockIdx.x;
  const int tx = threadIdx.x, ty = threadIdx.y;
  const int tid = ty * 32 + tx;
  if (Bk < 2048) {
    long b = Bk;
    int x = (int)(b & 31), y = (int)((b >> 5) & 7), z = (int)(b >> 8);
    int l = z & 3;
    const float* ip = (z < 4 ? ff1_w1 : ff2_w1) + (long)l * 512 * 2048;
    u16* op = (z < 4 ? wt_ff1w1 : wt_ff2w1) + (long)l * 512 * 2048;
    tbody64(ip, op, 512, 2048, x * 64, y * 64, tid);
  } else if (Bk < 4096) {
    long b = Bk - 2048;
    int x = (int)(b & 7), y = (int)((b >> 3) & 31), z = (int)(b >> 8);
    int l = z & 3;
    const float* ip = (z < 4 ? ff1_w2 : ff2_w2) + (long)l * 512 * 2048;
    u16* op = (z < 4 ? wt_ff1w2 : wt_ff2w2) + (long)l * 512 * 2048;
    tbody64(ip, op, 2048, 512, x * 64, y * 64, tid);
  } else if (Bk < 5376) {
    long b = Bk - 4096;
    int x = (int)(b & 7), y = (int)((b >> 3) & 7), z = (int)(b >> 6);
    int sel = z >> 2, l = z & 3;
    const float* ip;
    u16* op;
    const long S = 512L * 512;
    switch (sel) {
      case 0: ip = Wq + l * S; op = wt_qkv + (long)l * 1536 * 512; break;
      case 1: ip = Wk + l * S; op = wt_qkv + (long)l * 1536 * 512 + S; break;
      case 2: ip = Wv + l * S; op = wt_qkv + (long)l * 1536 * 512 + 2 * S; break;
      case 3: ip = Wo + l * S; op = wt_o + l * S; break;
      default: ip = Wpos + l * S; op = wt_pos + l * S; break;
    }
    tbody64(ip, op, 512, 512, x * 64, y * 64, tid);
  } else if (Bk < 7424) {
    long b = Bk - 5376;
    int x = (int)(b & 511), l = (int)(b >> 9);
    long i = (long)x * 256 + tid;
    long n = i >> 7;
    int c = (int)(i & 127) * 4;
    int q = (int)(n >> 4) & 1;
    long r = (q ? 512 : 0) + ((n >> 5) << 4) + (n & 15);
    const float* ip = pw1_w + ((long)l * 1024 + r) * 512 + c;
    float4 v = *(const float4*)ip;
    u16* op = w_pw1p + ((long)l * 1024 + n) * 512 + c;
    uint2 st;
    st.x = pack2(v.x, v.y);
    st.y = pack2(v.z, v.w);
    *(uint2*)op = st;
  } else if (Bk < 8448) {
    long b = Bk - 7424;
    int x = (int)(b & 255), l = (int)(b >> 8);
    long i = ((long)x * 256 + tid) * 4;
    const float* ip = pw2_w + (long)l * 512 * 512 + i;
    u16* op = w_pw2 + (long)l * 512 * 512 + i;
    float4 v = *(const float4*)ip;
    uint2 st;
    st.x = pack2(v.x, v.y);
    st.y = pack2(v.z, v.w);
    *(uint2*)op = st;
  } else if (Bk < 9984) {
    long b = Bk - 8448;
    int x = (int)(b & 511), y = (int)(b >> 9);
    if (y == 0) {
      long i = ((long)x * 256 + tid) * 4;
      const long nIn = 1023L * 512, nOut = 1024L * 512;
      if (i >= nOut) return;
      u16 o[4];
#pragma unroll
      for (int j = 0; j < 4; ++j) {
        long idx = i + j;
        o[j] = (idx < nIn) ? f2bf(in_pos[idx]) : (u16)0;
      }
      uint2 st;
      st.x = (u32)o[0] | ((u32)o[1] << 16);
      st.y = (u32)o[2] | ((u32)o[3] << 16);
      *(uint2*)&posbf[i] = st;
    } else if (y == 1) {
      long idx = (long)x * 256 + tid;
      if (idx >= 4L * 31 * 512) return;
      long l = idx / (31 * 512);
      int rem = (int)(idx % (31 * 512));
      int k = rem >> 9, d = rem & 511;
      dwT[idx] = dw_w[l * 512 * 31 + d * 31 + k];
    } else {
      long idx = (long)x * 256 + tid;
      if (idx >= 4L * 1536) return;
      int z = (int)(idx / 1536), j = (int)(idx % 1536);
      float v;
      if (j < 512) v = bq[z * 512 + j];
      else if (j < 1024) v = bk[z * 512 + j - 512];
      else v = bv[z * 512 + j - 1024];
      qkvb[idx] = v;
    }
  } else {
    long b = Bk - 9984;
    int wid = tid >> 6, lane = tid & 63;
    long row = b * 4 + wid;
    const float* x = in_x + row * CD + lane * 8;
    float v[8];
    *(float4*)&v[0] = *(const float4*)x;
    *(float4*)&v[4] = *(const float4*)(x + 4);
    float* cx = cur + row * CD + lane * 8;
    *(float4*)cx = *(float4*)&v[0];
    *(float4*)(cx + 4) = *(float4*)&v[4];
    float s = 0.f, q = 0.f;
#pragma unroll
    for (int j = 0; j < 8; ++j) { s += v[j]; q += v[j] * v[j]; }
    s = wsum(s);
    q = wsum(q);
    float mean = s * (1.0f / CD);
    float var = q * (1.0f / CD) - mean * mean;
    float rs = rsqrtf(var + 1e-5f);
    int c = lane * 8;
    float y[8];
#pragma unroll
    for (int j = 0; j < 8; ++j) y[j] = (v[j] - mean) * rs * ln1_g[c + j] + ln1_b[c + j];
    u16* o = ybf + row * CD + c;
    uint4 pk;
    pk.x = pack2(y[0], y[1]);
    pk.y = pack2(y[2], y[3]);
    pk.z = pack2(y[4], y[5]);
    pk.w = pack2(y[6], y[7]);
    *(uint4*)o = pk;
  }
}

// ------------------------------- LayerNorm ---------------------------------
template <int F32OUT>
__global__ __launch_bounds__(256) void ln_k(const float* in, void* out,
                                            const float* gw, const float* bw) {
  int tid = threadIdx.x, wid = tid >> 6, lane = tid & 63;
  long row = (long)blockIdx.x * 4 + wid;
  const float* x = in + row * CD + lane * 8;
  float4 v0 = *(const float4*)x;
  float4 v1 = *(const float4*)(x + 4);
  float s = v0.x + v0.y + v0.z + v0.w + v1.x + v1.y + v1.z + v1.w;
  float q = v0.x * v0.x + v0.y * v0.y + v0.z * v0.z + v0.w * v0.w +
            v1.x * v1.x + v1.y * v1.y + v1.z * v1.z + v1.w * v1.w;
  s = wsum(s);
  q = wsum(q);
  float mean = s * (1.0f / CD);
  float var = q * (1.0f / CD) - mean * mean;
  float rs = rsqrtf(var + 1e-5f);
  int c = lane * 8;
  float4 g0 = *(const float4*)(gw + c), g1 = *(const float4*)(gw + c + 4);
  float4 b0 = *(const float4*)(bw + c), b1 = *(const float4*)(bw + c + 4);
  float y0 = (v0.x - mean) * rs * g0.x + b0.x;
  float y1 = (v0.y - mean) * rs * g0.y + b0.y;
  float y2 = (v0.z - mean) * rs * g0.z + b0.z;
  float y3 = (v0.w - mean) * rs * g0.w + b0.w;
  float y4 = (v1.x - mean) * rs * g1.x + b1.x;
  float y5 = (v1.y - mean) * rs * g1.y + b1.y;
  float y6 = (v1.z - mean) * rs * g1.z + b1.z;
  float y7 = (v1.w - mean) * rs * g1.w + b1.w;
  if (F32OUT) {
    float* o = (float*)out + row * CD + c;
    *(float4*)o = make_float4(y0, y1, y2, y3);
    *(float4*)(o + 4) = make_float4(y4, y5, y6, y7);
  } else {
    u16* o = (u16*)out + row * CD + c;
    uint4 pk;
    pk.x = pack2(y0, y1);
    pk.y = pack2(y2, y3);
    pk.z = pack2(y4, y5);
    pk.w = pack2(y6, y7);
    *(uint4*)o = pk;
  }
}

// fused lnO (fp32 -> cur) + ln1-of-next-layer (bf16 -> ybf), one read pass
__global__ __launch_bounds__(256) void lnln_k(float* cur, u16* ybf,
                                              const float* gO, const float* bO,
                                              const float* g1, const float* b1) {
  int tid = threadIdx.x, wid = tid >> 6, lane = tid & 63;
  long row = (long)blockIdx.x * 4 + wid;
  float* x = cur + row * CD + lane * 8;
  float v[8];
  *(float4*)&v[0] = *(const float4*)x;
  *(float4*)&v[4] = *(const float4*)(x + 4);
  float s = 0.f, q = 0.f;
#pragma unroll
  for (int j = 0; j < 8; ++j) { s += v[j]; q += v[j] * v[j]; }
  s = wsum(s);
  q = wsum(q);
  float mean = s * (1.0f / CD);
  float var = q * (1.0f / CD) - mean * mean;
  float rs = rsqrtf(var + 1e-5f);
  int c = lane * 8;
  float y[8];
#pragma unroll
  for (int j = 0; j < 8; ++j) y[j] = (v[j] - mean) * rs * gO[c + j] + bO[c + j];
  *(float4*)x = *(float4*)&y[0];
  *(float4*)(x + 4) = *(float4*)&y[4];
  float s2 = 0.f, q2 = 0.f;
#pragma unroll
  for (int j = 0; j < 8; ++j) { s2 += y[j]; q2 += y[j] * y[j]; }
  s2 = wsum(s2);
  q2 = wsum(q2);
  float mean2 = s2 * (1.0f / CD);
  float var2 = q2 * (1.0f / CD) - mean2 * mean2;
  float rs2 = rsqrtf(var2 + 1e-5f);
  float z[8];
#pragma unroll
  for (int j = 0; j < 8; ++j) z[j] = (y[j] - mean2) * rs2 * g1[c + j] + b1[c + j];
  u16* o = ybf + row * CD + c;
  uint4 pk;
  pk.x = pack2(z[0], z[1]);
  pk.y = pack2(z[2], z[3]);
  pk.z = pack2(z[4], z[5]);
  pk.w = pack2(z[6], z[7]);
  *(uint4*)o = pk;
}

// --------------------------------- GEMM v2 (64x64) -------------------------
// Round-9 proven config: 3-buffer, vmcnt(4) + __syncthreads per K-tile.
// EPI: 0 store bf16 | 3 res += alpha*(v+bias)
template <int EPI, int SPLITK>
__global__ __launch_bounds__(256, 2) void gemm2_k(
    const u16* __restrict__ A, const u16* __restrict__ B, void* C,
    const float* __restrict__ bias, float alpha, int lda, int ldb, int ldc, int Kd) {
  __shared__ u16 lds[3][2][64 * 64];  // [buf][A/B][row*64]
  const int tid = threadIdx.x, wid = tid >> 6, lane = tid & 63;
  const int m0 = blockIdx.x * 64, n0 = blockIdx.y * 64;
  const int wm = wid >> 1, wn = wid & 1;
  const int fr = lane & 15, fq = lane >> 4;
  const f32x4 vz = {0.f, 0.f, 0.f, 0.f};
  f32x4 acc[2][2] = {{vz, vz}, {vz, vz}};

  const int Kc = Kd / SPLITK;
  const int kb0 = (SPLITK > 1) ? blockIdx.z * Kc : 0;
  const int nK = Kc / 64;

  auto stage = [&](int buf, int kt) {
    const int k0 = kb0 + kt * 64;
#pragma unroll
    for (int r = 0; r < 2; ++r) {
      int bi = r * 4096 + tid * 16;
      int row = bi >> 7;
      int ch = ((bi >> 4) & 7) ^ (row & 7);  // inverse swizzle on source
      gload16(A + (long)(m0 + row) * lda + k0 + ch * 8,
              (char*)&lds[buf][0][0] + r * 4096 + wid * 1024);
      gload16(B + (long)(n0 + row) * ldb + k0 + ch * 8,
              (char*)&lds[buf][1][0] + r * 4096 + wid * 1024);
    }
  };

  stage(0, 0);
  if (nK > 1) stage(1, 1);
  for (int kt = 0; kt < nK; ++kt) {
    const int buf = kt % 3;
    if (kt + 1 < nK)
      asm volatile("s_waitcnt vmcnt(4)" ::: "memory");
    else
      asm volatile("s_waitcnt vmcnt(0)" ::: "memory");
    __syncthreads();
    if (kt + 2 < nK) stage((kt + 2) % 3, kt + 2);
    bf16x8 af[2][2], bfv[2][2];
#pragma unroll
    for (int ks = 0; ks < 2; ++ks) {
      int ch = ks * 4 + fq;
#pragma unroll
      for (int i = 0; i < 2; ++i) {
        int arow = wm * 32 + i * 16 + fr;
        af[ks][i] = *(const bf16x8*)((const char*)&lds[buf][0][0] + arow * 128 +
                                     ((ch ^ (arow & 7)) << 4));
        int brow = wn * 32 + i * 16 + fr;
        bfv[ks][i] = *(const bf16x8*)((const char*)&lds[buf][1][0] + brow * 128 +
                                      ((ch ^ (brow & 7)) << 4));
      }
    }
#pragma unroll
    for (int ks = 0; ks < 2; ++ks)
#pragma unroll
      for (int mi = 0; mi < 2; ++mi)
#pragma unroll
        for (int ni = 0; ni < 2; ++ni)
          acc[mi][ni] = MFMA(af[ks][mi], bfv[ks][ni], acc[mi][ni]);
  }

#pragma unroll
  for (int mi = 0; mi < 2; ++mi) {
    const int gmB = m0 + wm * 32 + mi * 16 + fq * 4;
#pragma unroll
    for (int ni = 0; ni < 2; ++ni) {
      const int gn = n0 + wn * 32 + ni * 16 + fr;
      float bv_ = 0.f;
      if constexpr (EPI == 3) bv_ = bias[gn];
#pragma unroll
      for (int r = 0; r < 4; ++r) {
        const int gm = gmB + r;
        float v = acc[mi][ni][r];
        long idx = (long)gm * ldc + gn;
        if constexpr (EPI == 0) ((u16*)C)[idx] = f2bf(v);
        else if constexpr (EPI == 3) {
          float* R = (float*)C;
          if constexpr (SPLITK > 1) {
            float add = alpha * (v + (blockIdx.z == 0 ? bv_ : 0.f));
            atomicAdd(&R[idx], add);
          } else {
            R[idx] += alpha * (v + bv_);
          }
        }
      }
    }
  }
}

// --------------------------------- GEMM vB (128x128) -----------------------
// Round-9 proven config: BK=64, 2-buf, vmcnt(0)+__syncthreads per tile,
// XCD-bijective tile swizzle (T1; grid %8==0).
// EPI: 2 +bias swish | 7 GLU-packed | 8 qkv (+v-transpose to Caux)
template <int EPI>
__global__ __launch_bounds__(256, 2) void gemmB_k(
    const u16* __restrict__ A, const u16* __restrict__ B, void* C,
    u16* __restrict__ Caux, const float* __restrict__ bias,
    int lda, int ldb, int ldc, int Kd) {
  __shared__ u16 ldsA[2][128 * 64];
  __shared__ u16 ldsB[2][128 * 64];
  const int tid = threadIdx.x, wid = tid >> 6, lane = tid & 63;
  const int nwg = gridDim.x * gridDim.y;
  int lin = blockIdx.y * gridDim.x + blockIdx.x;
  lin = (lin & 7) * (nwg >> 3) + (lin >> 3);
  const int m0 = (lin % gridDim.x) * 128, n0 = (lin / gridDim.x) * 128;
  const int wm = wid >> 1, wn = wid & 1;
  const int fr = lane & 15, fq = lane >> 4;
  const f32x4 vz = {0.f, 0.f, 0.f, 0.f};
  f32x4 acc[4][4];
#pragma unroll
  for (int mi = 0; mi < 4; ++mi)
#pragma unroll
    for (int ni = 0; ni < 4; ++ni) acc[mi][ni] = vz;
  const int nK = Kd / 64;

  auto stage = [&](int buf, int kt) {
    const int k0 = kt * 64;
#pragma unroll
    for (int r = 0; r < 4; ++r) {
      int bi = r * 4096 + tid * 16;
      int row = bi >> 7;  // 128 B per 64-elem bf16 row
      int ch = ((bi >> 4) & 7) ^ (row & 7);
      gload16(A + (long)(m0 + row) * lda + k0 + ch * 8,
              (char*)&ldsA[buf][0] + r * 4096 + wid * 1024);
      gload16(B + (long)(n0 + row) * ldb + k0 + ch * 8,
              (char*)&ldsB[buf][0] + r * 4096 + wid * 1024);
    }
  };

  stage(0, 0);
  asm volatile("s_waitcnt vmcnt(0)" ::: "memory");
  __syncthreads();
  int buf = 0;
  for (int kt = 0; kt < nK; ++kt) {
    if (kt + 1 < nK) stage(buf ^ 1, kt + 1);
#pragma unroll
    for (int ks = 0; ks < 2; ++ks) {
      int ch = ks * 4 + fq;
      bf16x8 af[4], bfv[4];
#pragma unroll
      for (int i = 0; i < 4; ++i) {
        int arow = wm * 64 + i * 16 + fr;
        af[i] = *(const bf16x8*)((const char*)&ldsA[buf][0] + arow * 128 +
                                 ((ch ^ (arow & 7)) << 4));
        int brow = wn * 64 + i * 16 + fr;
        bfv[i] = *(const bf16x8*)((const char*)&ldsB[buf][0] + brow * 128 +
                                  ((ch ^ (brow & 7)) << 4));
      }
#pragma unroll
      for (int mi = 0; mi < 4; ++mi)
#pragma unroll
        for (int ni = 0; ni < 4; ++ni)
          acc[mi][ni] = MFMA(af[mi], bfv[ni], acc[mi][ni]);
    }
    asm volatile("s_waitcnt vmcnt(0)" ::: "memory");
    __syncthreads();
    buf ^= 1;
  }

  if constexpr (EPI == 2) {
#pragma unroll
    for (int mi = 0; mi < 4; ++mi) {
      const int gmB = m0 + wm * 64 + mi * 16 + fq * 4;
#pragma unroll
      for (int ni = 0; ni < 4; ++ni) {
        const int gn = n0 + wn * 64 + ni * 16 + fr;
        float bv_ = bias[gn];
#pragma unroll
        for (int r = 0; r < 4; ++r) {
          float x = acc[mi][ni][r] + bv_;
          ((u16*)C)[(long)(gmB + r) * ldc + gn] = f2bf(x * sigm(x));
        }
      }
    }
  } else if constexpr (EPI == 7) {
#pragma unroll
    for (int mi = 0; mi < 4; ++mi) {
      const int gmB = m0 + wm * 64 + mi * 16 + fq * 4;
#pragma unroll
      for (int p = 0; p < 2; ++p) {
        const int ucol = (n0 >> 1) + wn * 32 + p * 16 + fr;
        float ba = bias[ucol], bg = bias[512 + ucol];
#pragma unroll
        for (int r = 0; r < 4; ++r) {
          float va = acc[mi][2 * p][r] + ba;
          float vg = acc[mi][2 * p + 1][r] + bg;
          ((u16*)C)[(long)(gmB + r) * 512 + ucol] = f2bf(va * sigm(vg));
        }
      }
    }
  } else if constexpr (EPI == 8) {
    if (n0 < 1024) {
#pragma unroll
      for (int mi = 0; mi < 4; ++mi) {
        const int gmB = m0 + wm * 64 + mi * 16 + fq * 4;
#pragma unroll
        for (int ni = 0; ni < 4; ++ni) {
          const int gn = n0 + wn * 64 + ni * 16 + fr;
          float bv_ = bias[gn];
#pragma unroll
          for (int r = 0; r < 4; ++r)
            ((u16*)C)[(long)(gmB + r) * ldc + gn] = f2bf(acc[mi][ni][r] + bv_);
        }
      }
    } else {
#pragma unroll
      for (int mi = 0; mi < 4; ++mi) {
        const int gmB = m0 + wm * 64 + mi * 16 + fq * 4;
        const int b = gmB >> 9, t = gmB & 511;
#pragma unroll
        for (int ni = 0; ni < 4; ++ni) {
          const int gn = n0 + wn * 64 + ni * 16 + fr;
          const int h = (gn - 1024) >> 6, d = (gn - 1024) & 63;
          float bv_ = bias[gn];
          uint2 pk;
          pk.x = pack2(acc[mi][ni][0] + bv_, acc[mi][ni][1] + bv_);
          pk.y = pack2(acc[mi][ni][2] + bv_, acc[mi][ni][3] + bv_);
          *(uint2*)&Caux[((long)(b * 8 + h) * 64 + d) * 512 + t] = pk;
        }
      }
    }
  }
}

// ---------------- fused rel-pos flash attention v2 -------------------------
__global__ __launch_bounds__(256, 2) void attn_k(
    const u16* __restrict__ qkvp, const u16* __restrict__ pball,
    const float* __restrict__ pbuL, const float* __restrict__ pbvL,
    const u16* __restrict__ vt, u16* __restrict__ out) {
  __shared__ u16 ldsK[2][64 * 64];    // [s][d] swizzled
  __shared__ u16 ldsP[2][128 * 64];   // [j][d] swizzled
  __shared__ u16 bd0s[4][16 * 80];    // per-wave bd band
  __shared__ u16 stile[4][16 * 64];   // per-wave P (swizzled rows)
  const int tid = threadIdx.x, wid = tid >> 6, lane = tid & 63;
  const int t0 = blockIdx.x * 64;
  const int bh = blockIdx.y, b = bh >> 3, h = bh & 7;
  const int fr = lane & 15, fq = lane >> 4;

  const u16* kbase = qkvp + (long)(b * CT) * 1536 + 512 + h * 64;
  const u16* pbase = pball + h * 64;
  const float* pu = pbuL + h * 64;
  const float* pv = pbvL + h * 64;

  const u16* qp = qkvp + (long)(b * CT + t0 + wid * 16 + fr) * 1536 + h * 64;
  bf16x8 qua[2], qva[2];
#pragma unroll
  for (int kk = 0; kk < 2; ++kk) {
    bf16x8 qw = *(const bf16x8*)(qp + kk * 32 + fq * 8);
    const float* bu = pu + kk * 32 + fq * 8;
    const float* bv = pv + kk * 32 + fq * 8;
#pragma unroll
    for (int j = 0; j < 8; ++j) {
      float qf = bf2f((u16)qw[j]);
      qua[kk][j] = (short)f2bf(qf + bu[j]);
      qva[kk][j] = (short)f2bf(qf + bv[j]);
    }
  }

  const f32x4 vz = {0.f, 0.f, 0.f, 0.f};
  f32x4 oacc[4] = {vz, vz, vz, vz};
  float m_run[4] = {-1e30f, -1e30f, -1e30f, -1e30f};
  float l_run[4] = {0.f, 0.f, 0.f, 0.f};
  const int jbw = (3 - wid) * 16;

  auto stage = [&](int buf, int st) {
    int s0 = st * 64, j0 = s0 - t0 + 448;
#pragma unroll
    for (int r = 0; r < 2; ++r) {
      int c = r * 256 + tid;
      int row = c >> 3, cs = (c & 7) ^ (row & 7);
      gload16(kbase + (long)(s0 + row) * 1536 + cs * 8,
              (char*)&ldsK[buf][0] + r * 4096 + wid * 1024);
    }
#pragma unroll
    for (int r = 0; r < 4; ++r) {
      int c = r * 256 + tid;
      int row = c >> 3, cs = (c & 7) ^ (row & 7);
      gload16(pbase + (long)(j0 + row) * 2048 + cs * 8,
              (char*)&ldsP[buf][0] + r * 4096 + wid * 1024);
    }
  };

  stage(0, 0);
  int cur = 0;
  for (int st = 0; st < 8; ++st) {
    const int s0 = st * 64;
    if (st + 1 < 8) {
      stage(cur ^ 1, st + 1);
      asm volatile("s_waitcnt vmcnt(6)" ::: "memory");
    } else {
      asm volatile("s_waitcnt vmcnt(0)" ::: "memory");
    }
    __syncthreads();

    bf16x8 vb[4][2];
#pragma unroll
    for (int ni = 0; ni < 4; ++ni)
#pragma unroll
      for (int kk = 0; kk < 2; ++kk)
        vb[ni][kk] = *(const bf16x8*)&vt[((long)bh * 64 + ni * 16 + fr) * 512 +
                                         s0 + kk * 32 + fq * 8];

    __builtin_amdgcn_s_setprio(1);
    f32x4 ac[4] = {vz, vz, vz, vz};
#pragma unroll
    for (int kk = 0; kk < 2; ++kk) {
#pragma unroll
      for (int ni = 0; ni < 4; ++ni) {
        int row = ni * 16 + fr;
        bf16x8 kb = *(const bf16x8*)((const char*)&ldsK[cur][0] +
                                     ((row * 128 + kk * 64 + fq * 16) ^ ((row & 7) << 4)));
        ac[ni] = MFMA(qua[kk], kb, ac[ni]);
      }
    }
    f32x4 bd[5] = {vz, vz, vz, vz, vz};
#pragma unroll
    for (int kk = 0; kk < 2; ++kk) {
#pragma unroll
      for (int nbi = 0; nbi < 5; ++nbi) {
        int row = jbw + nbi * 16 + fr;
        bf16x8 pb = *(const bf16x8*)((const char*)&ldsP[cur][0] +
                                     ((row * 128 + kk * 64 + fq * 16) ^ ((row & 7) << 4)));
        bd[nbi] = MFMA(qva[kk], pb, bd[nbi]);
      }
    }
    __builtin_amdgcn_s_setprio(0);
#pragma unroll
    for (int nbi = 0; nbi < 5; ++nbi)
#pragma unroll
      for (int r = 0; r < 4; ++r)
        bd0s[wid][(fq * 4 + r) * 80 + nbi * 16 + fr] = f2bf(bd[nbi][r]);

    float vals[4][4];
#pragma unroll
    for (int ni = 0; ni < 4; ++ni)
#pragma unroll
      for (int r = 0; r < 4; ++r) {
        int tlw = fq * 4 + r;
        int jcol = ni * 16 + fr + 15 - tlw;
        vals[ni][r] = (ac[ni][r] + bf2f(bd0s[wid][tlw * 80 + jcol])) * 0.125f;
      }
    float scf[4];
#pragma unroll
    for (int r = 0; r < 4; ++r) {
      float mx = fmaxf(fmaxf(vals[0][r], vals[1][r]), fmaxf(vals[2][r], vals[3][r]));
      mx = fmaxf(mx, __shfl_xor(mx, 1));
      mx = fmaxf(mx, __shfl_xor(mx, 2));
      mx = fmaxf(mx, __shfl_xor(mx, 4));
      mx = fmaxf(mx, __shfl_xor(mx, 8));
      float mnew = fmaxf(m_run[r], mx);
      scf[r] = __expf(m_run[r] - mnew);
      m_run[r] = mnew;
      float sum = 0.f;
#pragma unroll
      for (int ni = 0; ni < 4; ++ni) {
        float p = __expf(vals[ni][r] - mnew);
        vals[ni][r] = p;
        sum += p;
      }
      sum += __shfl_xor(sum, 1);
      sum += __shfl_xor(sum, 2);
      sum += __shfl_xor(sum, 4);
      sum += __shfl_xor(sum, 8);
      l_run[r] = l_run[r] * scf[r] + sum;
    }
#pragma unroll
    for (int ni = 0; ni < 4; ++ni)
#pragma unroll
      for (int r = 0; r < 4; ++r) {
        int tlw = fq * 4 + r;
        *(u16*)((char*)&stile[wid][0] +
                (((tlw * 128) + (ni * 16 + fr) * 2) ^ ((tlw & 7) << 4))) =
            f2bf(vals[ni][r]);
      }
#pragma unroll
    for (int ni = 0; ni < 4; ++ni)
#pragma unroll
      for (int r = 0; r < 4; ++r) oacc[ni][r] *= scf[r];
    __builtin_amdgcn_s_setprio(1);
#pragma unroll
    for (int kk = 0; kk < 2; ++kk) {
      bf16x8 pa = *(const bf16x8*)((const char*)&stile[wid][0] +
                                   ((fr * 128 + kk * 64 + fq * 16) ^ ((fr & 7) << 4)));
#pragma unroll
      for (int ni = 0; ni < 4; ++ni) oacc[ni] = MFMA(pa, vb[ni][kk], oacc[ni]);
    }
    __builtin_amdgcn_s_setprio(0);
    __syncthreads();
    cur ^= 1;
  }

  float inv[4];
#pragma unroll
  for (int r = 0; r < 4; ++r) inv[r] = 1.0f / l_run[r];
#pragma unroll
  for (int ni = 0; ni < 4; ++ni)
#pragma unroll
    for (int r = 0; r < 4; ++r) {
      long row = (long)(b * CT + t0 + wid * 16 + fq * 4 + r) * CD + h * CDK;
      out[row + ni * 16 + fr] = f2bf(oacc[ni][r] * inv[r]);
    }
}

// ------------------------------ conv module --------------------------------
// depthwise conv(K=31,pad 15) + dw_b + LN(cln) + swish.
__global__ __launch_bounds__(256) void conv2_k(const u16* __restrict__ u,
                                               const float* __restrict__ wT,
                                               const float* __restrict__ wb,
                                               const float* __restrict__ cg,
                                               const float* __restrict__ cb,
                                               u16* __restrict__ out) {
  constexpr int TT = 8;
  int tid = threadIdx.x, d0 = tid * 2;
  int b = blockIdx.y, t0 = blockIdx.x * TT;
  const u16* ub = u + ((long)b * CT) * CD + d0;

  u32 strip[TT + 30];
#pragma unroll
  for (int j = 0; j < TT + 30; ++j) {
    int tt = t0 + j - 15;
    strip[j] = ((unsigned)tt < (unsigned)CT) ? *(const u32*)(ub + (long)tt * CD) : 0u;
  }
  float2 bias = *(const float2*)(wb + d0);
  float a0[TT], a1[TT];
#pragma unroll
  for (int t = 0; t < TT; ++t) { a0[t] = bias.x; a1[t] = bias.y; }
#pragma unroll
  for (int k = 0; k < 31; ++k) {
    float2 wk = *(const float2*)(wT + k * CD + d0);
#pragma unroll
    for (int t = 0; t < TT; ++t) {
      u32 pr = strip[t + k];
      a0[t] += bf2f((u16)(pr & 0xffff)) * wk.x;
      a1[t] += bf2f((u16)(pr >> 16)) * wk.y;
    }
  }
  __shared__ float redS[4][TT], redQ[4][TT];
  int wid = tid >> 6, lane = tid & 63;
#pragma unroll
  for (int t = 0; t < TT; ++t) {
    float s = a0[t] + a1[t];
    float q = a0[t] * a0[t] + a1[t] * a1[t];
    s = wsum(s);
    q = wsum(q);
    if (lane == 0) { redS[wid][t] = s; redQ[wid][t] = q; }
  }
  __syncthreads();
  float2 g2 = *(const float2*)(cg + d0);
  float2 b2 = *(const float2*)(cb + d0);
#pragma unroll
  for (int t = 0; t < TT; ++t) {
    float s = redS[0][t] + redS[1][t] + redS[2][t] + redS[3][t];
    float q = redQ[0][t] + redQ[1][t] + redQ[2][t] + redQ[3][t];
    float mean = s * (1.f / 512), var = q * (1.f / 512) - mean * mean;
    float rs = rsqrtf(var + 1e-5f);
    float y0 = (a0[t] - mean) * rs * g2.x + b2.x;
    float y1 = (a1[t] - mean) * rs * g2.y + b2.y;
    y0 = y0 * sigm(y0);
    y1 = y1 * sigm(y1);
    *(u32*)(out + ((long)(b * CT + t0 + t)) * CD + d0) = pack2(y0, y1);
  }
}

// ---------------------------------------------------------------------------
extern "C" void kernel_launch(void* const* d_in, const int* in_sizes, int n_in,
                              void* d_out, int out_size, void* d_ws, size_t ws_size,
                              hipStream_t stream) {
  const float* in_x   = (const float*)d_in[0];
  const float* in_pos = (const float*)d_in[1];
  const float* ln1_g  = (const float*)d_in[2];
  const float* ln1_b  = (const float*)d_in[3];
  const float* ff1_w1 = (const float*)d_in[4];
  const float* ff1_b1 = (const float*)d_in[5];
  const float* ff1_w2 = (const float*)d_in[6];
  const float* ff1_b2 = (const float*)d_in[7];
  const float* lnA_g  = (const float*)d_in[8];
  const float* lnA_b  = (const float*)d_in[9];
  const float* Wq     = (const float*)d_in[10];
  const float* bq     = (const float*)d_in[11];
  const float* Wk     = (const float*)d_in[12];
  const float* bk     = (const float*)d_in[13];
  const float* Wv     = (const float*)d_in[14];
  const float* bv     = (const float*)d_in[15];
  const float* Wo     = (const float*)d_in[16];
  const float* bo     = (const float*)d_in[17];
  const float* Wpos   = (const float*)d_in[18];
  const float* pbu    = (const float*)d_in[19];
  const float* pbv    = (const float*)d_in[20];
  const float* lnC_g  = (const float*)d_in[21];
  const float* lnC_b  = (const float*)d_in[22];
  const float* pw1_w  = (const float*)d_in[23];
  const float* pw1_b  = (const float*)d_in[24];
  const float* dw_w   = (const float*)d_in[25];
  const float* dw_b   = (const float*)d_in[26];
  const float* cln_g  = (const float*)d_in[27];
  const float* cln_b  = (const float*)d_in[28];
  const float* pw2_w  = (const float*)d_in[29];
  const float* pw2_b  = (const float*)d_in[30];
  const float* ln2_g  = (const float*)d_in[31];
  const float* ln2_b  = (const float*)d_in[32];
  const float* ff2_w1 = (const float*)d_in[33];
  const float* ff2_b1 = (const float*)d_in[34];
  const float* ff2_w2 = (const float*)d_in[35];
  const float* ff2_b2 = (const float*)d_in[36];
  const float* lnO_g  = (const float*)d_in[37];
  const float* lnO_b  = (const float*)d_in[38];
  (void)in_sizes; (void)n_in; (void)out_size; (void)ws_size;

  char* ws = (char*)d_ws;
  size_t off = 0;
  auto alloc = [&](size_t bytes) -> void* {
    off = (off + 255) & ~(size_t)255;
    void* p = ws + off;
    off += bytes;
    return p;
  };

  // weights (bf16, [N,K] layout)
  u16* wt_ff1w1 = (u16*)alloc((size_t)CL * CDFF * CD * 2);
  u16* wt_ff1w2 = (u16*)alloc((size_t)CL * CD * CDFF * 2);
  u16* wt_qkv   = (u16*)alloc((size_t)CL * 1536 * CD * 2);
  u16* wt_o     = (u16*)alloc((size_t)CL * CD * CD * 2);
  u16* wt_pos   = (u16*)alloc((size_t)CL * CD * CD * 2);
  u16* w_pw1p   = (u16*)alloc((size_t)CL * 1024 * CD * 2);
  u16* w_pw2    = (u16*)alloc((size_t)CL * CD * CD * 2);
  u16* wt_ff2w1 = (u16*)alloc((size_t)CL * CDFF * CD * 2);
  u16* wt_ff2w2 = (u16*)alloc((size_t)CL * CD * CDFF * 2);
  float* qkvbias = (float*)alloc((size_t)CL * 1536 * 4);
  u16* posbf = (u16*)alloc((size_t)1024 * CD * 2);
  float* dwT = (float*)alloc((size_t)CL * 31 * CD * 4);
  u16* pbf_all = (u16*)alloc((size_t)1024 * 2048 * 2);
  // activations
  float* cur = (float*)alloc((size_t)CNBT * CD * 4);
  u16* ybf   = (u16*)alloc((size_t)CNBT * CD * 2);
  u16* qkv   = (u16*)alloc((size_t)CNBT * 1536 * 2);
  u16* hbf   = (u16*)alloc((size_t)CNBT * CDFF * 2);
  u16* vt    = (u16*)alloc((size_t)64 * CDK * CT * 2);
  u16* obf   = (u16*)alloc((size_t)CNBT * CD * 2);
  u16* ubuf  = (u16*)alloc((size_t)CNBT * CD * 2);
  u16* cbf   = (u16*)alloc((size_t)CNBT * CD * 2);

  dim3 b256(256);
  dim3 tb(32, 8);

  // ---- setup: single merged kernel (weights, pos, biases, layer-0 LN) ----
  setupall_k<<<dim3(11008), tb, 0, stream>>>(
      ff1_w1, ff2_w1, wt_ff1w1, wt_ff2w1,
      ff1_w2, ff2_w2, wt_ff1w2, wt_ff2w2,
      Wq, Wk, Wv, Wo, Wpos, wt_qkv, wt_o, wt_pos,
      pw1_w, w_pw1p, pw2_w, w_pw2,
      in_pos, posbf, dw_w, dwT,
      bq, bk, bv, qkvbias,
      in_x, cur, ybf, ln1_g, ln1_b);
  // all-layer pos projection: pbf_all[j][l*512+c]
  gemm2_k<0, 1><<<dim3(16, 32, 1), b256, 0, stream>>>(
      posbf, wt_pos, pbf_all, nullptr, 0.f, CD, CD, 2048, CD);

  for (int i = 0; i < CL; ++i) {
    const u16* Wf1 = wt_ff1w1 + (long)i * CDFF * CD;
    const u16* Wf2 = wt_ff1w2 + (long)i * CD * CDFF;
    const u16* Wqk = wt_qkv + (long)i * 1536 * CD;
    const u16* Wou = wt_o + (long)i * CD * CD;
    const u16* Wp1 = w_pw1p + (long)i * 1024 * CD;
    const u16* Wp2 = w_pw2 + (long)i * CD * CD;
    const u16* Wf3 = wt_ff2w1 + (long)i * CDFF * CD;
    const u16* Wf4 = wt_ff2w2 + (long)i * CD * CDFF;

    // ---- FFN1 (half residual); ybf already = LN(cur; ln1) ----
    gemmB_k<2><<<dim3(32, 16, 1), b256, 0, stream>>>(
        ybf, Wf1, hbf, nullptr, ff1_b1 + (long)i * CDFF, CD, CD, CDFF, CD);
    gemm2_k<3, 1><<<dim3(64, 8, 1), b256, 0, stream>>>(
        hbf, Wf2, cur, ff1_b2 + i * CD, 0.5f, CDFF, CDFF, CD, CDFF);

    // ---- rel-pos MHSA (fused; V-transpose in QKV epilogue) ----
    ln_k<0><<<dim3(1024), b256, 0, stream>>>(cur, ybf, lnA_g + i * CD, lnA_b + i * CD);
    gemmB_k<8><<<dim3(32, 12, 1), b256, 0, stream>>>(
        ybf, Wqk, qkv, vt, qkvbias + i * 1536, CD, CD, 1536, CD);
    attn_k<<<dim3(8, 64), b256, 0, stream>>>(qkv, pbf_all + i * 512, pbu + i * 512,
                                             pbv + i * 512, vt, obf);
    gemm2_k<3, 1><<<dim3(64, 8, 1), b256, 0, stream>>>(
        obf, Wou, cur, bo + i * CD, 1.0f, CD, CD, CD, CD);

    // ---- conv module ----
    ln_k<0><<<dim3(1024), b256, 0, stream>>>(cur, ybf, lnC_g + i * CD, lnC_b + i * CD);
    gemmB_k<7><<<dim3(32, 8, 1), b256, 0, stream>>>(
        ybf, Wp1, ubuf, nullptr, pw1_b + (long)i * 1024, CD, CD, 512, CD);
    conv2_k<<<dim3(CT / 8, 8), b256, 0, stream>>>(ubuf, dwT + (long)i * 31 * CD,
                                                  dw_b + i * CD, cln_g + i * CD,
                                                  cln_b + i * CD, cbf);
    gemm2_k<3, 1><<<dim3(64, 8, 1), b256, 0, stream>>>(
        cbf, Wp2, cur, pw2_b + i * CD, 1.0f, CD, CD, CD, CD);

    // ---- FFN2 (half residual) ----
    ln_k<0><<<dim3(1024), b256, 0, stream>>>(cur, ybf, ln2_g + i * CD, ln2_b + i * CD);
    gemmB_k<2><<<dim3(32, 16, 1), b256, 0, stream>>>(
        ybf, Wf3, hbf, nullptr, ff2_b1 + (long)i * CDFF, CD, CD, CDFF, CD);
    gemm2_k<3, 1><<<dim3(64, 8, 1), b256, 0, stream>>>(
        hbf, Wf4, cur, ff2_b2 + i * CD, 0.5f, CDFF, CDFF, CD, CDFF);

    // ---- output LN (fused with next layer's ln1) ----
    if (i < CL - 1)
      lnln_k<<<dim3(1024), b256, 0, stream>>>(cur, ybf, lnO_g + i * CD, lnO_b + i * CD,
                                              ln1_g + (i + 1) * CD, ln1_b + (i + 1) * CD);
    else
      ln_k<1><<<dim3(1024), b256, 0, stream>>>(cur, d_out, lnO_g + i * CD, lnO_b + i * CD);
  }
}